// Round 1
// baseline (1575.871 us; speedup 1.0000x reference)
//
#include <hip/hip_runtime.h>
#include <hip/hip_bf16.h>

#define N_ 4
#define C_ 1024
#define D_ 768
#define H_ 12
#define E_ 24
#define M_ 4
#define P_ 552
#define R_ 97
#define HD_ 64
#define D3_ (3*D_)

#define SCALE_ 0.036084391824351615f  // 1/sqrt(768)

// ---------------- K1: ent_emb = logsumexp over M mentions ----------------
__global__ void k_ent_emb(const float* __restrict__ seq, const int* __restrict__ epos,
                          float* __restrict__ entEmb) {
    int idx = blockIdx.x * blockDim.x + threadIdx.x;   // over N*E*D
    if (idx >= N_*E_*D_) return;
    int d  = idx % D_;
    int ne = idx / D_;
    int e  = ne % E_;
    int n  = ne / E_;
    const int* pp = epos + (n*E_ + e)*M_;
    float v[M_];
    float mx = -1e30f;
    #pragma unroll
    for (int m = 0; m < M_; m++) {
        int pos = pp[m] + 1;  // OFFSET
        v[m] = seq[((long)n*C_ + pos)*D_ + d];
        mx = fmaxf(mx, v[m]);
    }
    float s = 0.f;
    #pragma unroll
    for (int m = 0; m < M_; m++) s += expf(v[m] - mx);
    entEmb[idx] = mx + logf(s);
}

// ---------------- K2: ent_att = mean over M of attention rows ----------------
__global__ void k_ent_att(const float* __restrict__ att, const int* __restrict__ epos,
                          float* __restrict__ entAtt) {
    long idx = (long)blockIdx.x * blockDim.x + threadIdx.x;  // over N*E*H*C
    if (idx >= (long)N_*E_*H_*C_) return;
    int c = idx % C_;
    long r = idx / C_;
    int h = r % H_; r /= H_;
    int e = r % E_;
    int n = r / E_;
    const int* pp = epos + (n*E_ + e)*M_;
    float s = 0.f;
    #pragma unroll
    for (int m = 0; m < M_; m++) {
        int pos = pp[m] + 1;
        s += att[(((long)n*H_ + h)*C_ + pos)*C_ + c];
    }
    entAtt[idx] = s * (1.0f / M_);
}

// ---------------- K3: gather hs/ts into concat buffer ----------------
__global__ void k_gather_ht(const float* __restrict__ entEmb, const int* __restrict__ hts,
                            float* __restrict__ cat) {
    int idx = blockIdx.x * blockDim.x + threadIdx.x;  // over N*P*D
    if (idx >= N_*P_*D_) return;
    int d  = idx % D_;
    int np = idx / D_;
    int p  = np % P_;
    int n  = np / P_;
    int hi = hts[(n*P_ + p)*2 + 0];
    int ti = hts[(n*P_ + p)*2 + 1];
    cat[(long)np*D3_ + d]       = entEmb[((long)n*E_ + hi)*D_ + d];
    cat[(long)np*D3_ + D_ + d]  = entEmb[((long)n*E_ + ti)*D_ + d];
}

// ---------------- K4: ht_att (mean over H of h_att*t_att, normalized over C) ----------------
__global__ void k_ht_att(const float* __restrict__ entAtt, const int* __restrict__ hts,
                         float* __restrict__ htAtt) {
    int np = blockIdx.x;           // N*P blocks
    int p = np % P_, n = np / P_;
    int t = threadIdx.x;           // 256 threads
    int hi = hts[(n*P_ + p)*2 + 0];
    int ti = hts[(n*P_ + p)*2 + 1];
    const float* ha = entAtt + ((long)n*E_ + hi)*H_*C_;
    const float* ta = entAtt + ((long)n*E_ + ti)*H_*C_;
    float vals[C_/256];
    float lsum = 0.f;
    #pragma unroll
    for (int i = 0; i < C_/256; i++) {
        int c = t + i*256;
        float s = 0.f;
        #pragma unroll
        for (int h = 0; h < H_; h++) s += ha[h*C_ + c] * ta[h*C_ + c];
        s *= (1.0f / H_);
        vals[i] = s;
        lsum += s;
    }
    __shared__ float red[256];
    red[t] = lsum; __syncthreads();
    for (int s1 = 128; s1; s1 >>= 1) { if (t < s1) red[t] += red[t+s1]; __syncthreads(); }
    float inv = 1.0f / (red[0] + 1e-5f);
    #pragma unroll
    for (int i = 0; i < C_/256; i++)
        htAtt[(long)np*C_ + t + i*256] = vals[i] * inv;
}

// ---------------- generic tiled f32 GEMM: C = act(A*B + bias) ----------------
// A: MxK (lda), B: KxN (ldb), C: MxN (ldc). K % 16 == 0 assumed.
__global__ __launch_bounds__(256) void k_gemm(
        const float* __restrict__ A, const float* __restrict__ B,
        const float* __restrict__ bias, float* __restrict__ C,
        int M, int N, int K, int lda, int ldb, int ldc,
        long sA, long sB, long sC, int act) {
    int batch = blockIdx.z;
    A += (long)batch * sA; B += (long)batch * sB; C += (long)batch * sC;
    __shared__ float As[16][64+1];
    __shared__ float Bs[16][64];
    int t = threadIdx.x;
    int m0 = blockIdx.y * 64, n0 = blockIdx.x * 64;
    int tm = t >> 4, tn = t & 15;
    float acc[4][4] = {};
    int kkA = t & 15, mA = t >> 4;   // A-tile loader coords
    int nnB = t & 63, kB = t >> 6;   // B-tile loader coords
    for (int k0 = 0; k0 < K; k0 += 16) {
        #pragma unroll
        for (int i = 0; i < 4; i++) {
            int m = mA + i*16;
            int gm = m0 + m;
            As[kkA][m] = (gm < M) ? A[(long)gm*lda + k0 + kkA] : 0.f;
        }
        #pragma unroll
        for (int i = 0; i < 4; i++) {
            int kkb = kB + i*4;
            int gn = n0 + nnB;
            Bs[kkb][nnB] = (gn < N) ? B[(long)(k0+kkb)*ldb + gn] : 0.f;
        }
        __syncthreads();
        #pragma unroll
        for (int kk = 0; kk < 16; kk++) {
            float a[4], b[4];
            #pragma unroll
            for (int i = 0; i < 4; i++) a[i] = As[kk][tm*4+i];
            #pragma unroll
            for (int j = 0; j < 4; j++) b[j] = Bs[kk][tn*4+j];
            #pragma unroll
            for (int i = 0; i < 4; i++)
                #pragma unroll
                for (int j = 0; j < 4; j++)
                    acc[i][j] += a[i]*b[j];
        }
        __syncthreads();
    }
    #pragma unroll
    for (int i = 0; i < 4; i++) {
        int gm = m0 + tm*4 + i;
        if (gm >= M) continue;
        #pragma unroll
        for (int j = 0; j < 4; j++) {
            int gn = n0 + tn*4 + j;
            if (gn >= N) continue;
            float v = acc[i][j] + (bias ? bias[gn] : 0.f);
            if (act == 1) v = tanhf(v);
            C[(long)gm*ldc + gn] = v;
        }
    }
}

// ---------------- K9: attention over R=97 rels, fused (one wave per (np,h)) ----------------
__global__ void k_attn1(const float* __restrict__ qb, const float* __restrict__ kb,
                        const float* __restrict__ vb, float* __restrict__ o1) {
    int b = blockIdx.x;            // N*P*H blocks, 64 threads
    int h = b % H_;
    int np = b / H_;
    int lane = threadIdx.x;
    __shared__ float qs[64];
    __shared__ float wsm[128];
    qs[lane] = qb[(long)np*D_ + h*HD_ + lane];
    __syncthreads();
    float s0, s1 = -1e30f;
    {
        const float* kr = kb + (long)lane*D_ + h*HD_;
        float acc = 0.f;
        #pragma unroll
        for (int e = 0; e < 64; e++) acc += qs[e]*kr[e];
        s0 = acc * SCALE_;
    }
    if (lane + 64 < R_) {
        const float* kr = kb + (long)(lane+64)*D_ + h*HD_;
        float acc = 0.f;
        #pragma unroll
        for (int e = 0; e < 64; e++) acc += qs[e]*kr[e];
        s1 = acc * SCALE_;
    }
    float m = fmaxf(s0, s1);
    for (int off = 32; off; off >>= 1) m = fmaxf(m, __shfl_xor(m, off));
    float w0 = expf(s0 - m);
    float w1 = (lane + 64 < R_) ? expf(s1 - m) : 0.f;
    float ls = w0 + w1;
    for (int off = 32; off; off >>= 1) ls += __shfl_xor(ls, off);
    wsm[lane] = w0; wsm[64+lane] = w1;
    __syncthreads();
    float inv_l = 1.0f / ls;
    float acc = 0.f;
    for (int r = 0; r < R_; r++)
        acc += wsm[r] * vb[(long)r*D_ + h*HD_ + lane];
    o1[(long)np*D_ + h*HD_ + lane] = acc * inv_l;
}

// ---------------- K10: self-attention over P=552 (scores2), fused, 8 queries/block ----------------
#define G2 8
__global__ __launch_bounds__(256) void k_attn2(const float* __restrict__ o1, float* __restrict__ o2) {
    int pt = blockIdx.x;   // 0..P/G2-1
    int h  = blockIdx.y;
    int n  = blockIdx.z;
    int p0 = pt * G2;
    int t = threadIdx.x;
    const float* base = o1 + (long)n*P_*D_ + h*HD_;
    __shared__ float opS[G2][HD_];
    __shared__ float sArr[G2][P_];
    __shared__ float lS[G2];
    __shared__ float accS[4][G2][HD_];
    for (int i = t; i < G2*HD_; i += 256) {
        int pi = i / HD_, e = i % HD_;
        opS[pi][e] = base[(long)(p0+pi)*D_ + e];
    }
    __syncthreads();
    // score phase
    for (int q = t; q < P_; q += 256) {
        const float* row = base + (long)q*D_;
        float acc[G2];
        #pragma unroll
        for (int pi = 0; pi < G2; pi++) acc[pi] = 0.f;
        for (int e = 0; e < HD_; e++) {
            float rv = row[e];
            #pragma unroll
            for (int pi = 0; pi < G2; pi++) acc[pi] += opS[pi][e]*rv;
        }
        #pragma unroll
        for (int pi = 0; pi < G2; pi++) sArr[pi][q] = acc[pi]*SCALE_;
    }
    __syncthreads();
    // softmax: wave w owns rows 2w, 2w+1
    int wv = t >> 6, lane = t & 63;
    for (int pi = wv*2; pi < wv*2+2; pi++) {
        float m = -1e30f;
        for (int q = lane; q < P_; q += 64) m = fmaxf(m, sArr[pi][q]);
        for (int off = 32; off; off >>= 1) m = fmaxf(m, __shfl_xor(m, off));
        float ls = 0.f;
        for (int q = lane; q < P_; q += 64) {
            float w = expf(sArr[pi][q] - m);
            sArr[pi][q] = w;
            ls += w;
        }
        for (int off = 32; off; off >>= 1) ls += __shfl_xor(ls, off);
        if (lane == 0) lS[pi] = ls;
    }
    __syncthreads();
    // accumulate phase
    int e = t & 63, g = t >> 6;
    float acc[G2];
    #pragma unroll
    for (int pi = 0; pi < G2; pi++) acc[pi] = 0.f;
    for (int q = g; q < P_; q += 4) {
        float rv = base[(long)q*D_ + e];
        #pragma unroll
        for (int pi = 0; pi < G2; pi++) acc[pi] += sArr[pi][q]*rv;
    }
    #pragma unroll
    for (int pi = 0; pi < G2; pi++) accS[g][pi][e] = acc[pi];
    __syncthreads();
    for (int i = t; i < G2*HD_; i += 256) {
        int pi = i / HD_, e2 = i % HD_;
        float v = (accS[0][pi][e2]+accS[1][pi][e2]+accS[2][pi][e2]+accS[3][pi][e2]) / lS[pi];
        o2[((long)n*P_ + p0+pi)*D_ + h*HD_ + e2] = v;
    }
}

// ---------------- K11: x = LN(htr + tanh(o2)) ----------------
__global__ void k_ln(const float* __restrict__ htr, const float* __restrict__ o2,
                     const float* __restrict__ g, const float* __restrict__ b,
                     float* __restrict__ x) {
    int np = blockIdx.x;    // N*P blocks
    int t = threadIdx.x;    // 256 threads
    __shared__ float red[256];
    float v[D_/256];
    float s = 0.f;
    #pragma unroll
    for (int i = 0; i < D_/256; i++) {
        int d = t + i*256;
        float val = htr[(long)np*D_ + d] + tanhf(o2[(long)np*D_ + d]);
        v[i] = val; s += val;
    }
    red[t] = s; __syncthreads();
    for (int s1 = 128; s1; s1 >>= 1) { if (t < s1) red[t] += red[t+s1]; __syncthreads(); }
    float mu = red[0] * (1.0f/D_);
    __syncthreads();
    float s2 = 0.f;
    #pragma unroll
    for (int i = 0; i < D_/256; i++) { float dx = v[i]-mu; s2 += dx*dx; }
    red[t] = s2; __syncthreads();
    for (int s1 = 128; s1; s1 >>= 1) { if (t < s1) red[t] += red[t+s1]; __syncthreads(); }
    float inv = rsqrtf(red[0]*(1.0f/D_) + 1e-5f);
    #pragma unroll
    for (int i = 0; i < D_/256; i++) {
        int d = t + i*256;
        x[(long)np*D_ + d] = (v[i]-mu)*inv*g[d] + b[d];
    }
}

extern "C" void kernel_launch(void* const* d_in, const int* in_sizes, int n_in,
                              void* d_out, int out_size, void* d_ws, size_t ws_size,
                              hipStream_t stream) {
    const float* seq   = (const float*)d_in[0];
    const float* att   = (const float*)d_in[1];
    const int*   epos  = (const int*)d_in[2];
    const int*   hts   = (const int*)d_in[3];
    const float* rels  = (const float*)d_in[4];
    const float* We    = (const float*)d_in[5];
    const float* be    = (const float*)d_in[6];
    const float* Wq    = (const float*)d_in[7];
    const float* bq    = (const float*)d_in[8];
    const float* Wk    = (const float*)d_in[9];
    const float* bk    = (const float*)d_in[10];
    const float* Wv    = (const float*)d_in[11];
    const float* bv    = (const float*)d_in[12];
    const float* ln_g  = (const float*)d_in[13];
    const float* ln_b  = (const float*)d_in[14];
    const float* Wc    = (const float*)d_in[15];
    const float* bc    = (const float*)d_in[16];
    float* out = (float*)d_out;
    float* w = (float*)d_ws;

    // workspace layout (floats)
    float* entEmb = w;                              // 73,728
    float* entAtt = entEmb + (size_t)N_*E_*D_;      // 1,179,648
    float* htAtt  = entAtt + (size_t)N_*E_*H_*C_;   // 2,260,992
    float* cat    = htAtt  + (size_t)N_*P_*C_;      // 5,087,232
    float* htr    = cat    + (size_t)N_*P_*D3_;     // 1,695,744
    float* qb     = htr    + (size_t)N_*P_*D_;      // 1,695,744
    float* kb     = qb     + (size_t)N_*P_*D_;      // 74,496
    float* vb     = kb     + (size_t)R_*D_;         // 74,496
    float* o1     = vb     + (size_t)R_*D_;         // 1,695,744
    float* o2     = o1     + (size_t)N_*P_*D_;      // 1,695,744
    float* xb     = o2     + (size_t)N_*P_*D_;      // 1,695,744

    const int NP = N_*P_;  // 2208

    k_ent_emb<<<(N_*E_*D_+255)/256, 256, 0, stream>>>(seq, epos, entEmb);
    k_ent_att<<<(N_*E_*H_*C_+255)/256, 256, 0, stream>>>(att, epos, entAtt);
    k_gather_ht<<<(N_*P_*D_+255)/256, 256, 0, stream>>>(entEmb, hts, cat);
    k_ht_att<<<NP, 256, 0, stream>>>(entAtt, hts, htAtt);

    // rs = batched ht_att(n) @ seq(n) -> cat[:, :, 2D:3D]
    k_gemm<<<dim3((D_+63)/64, (P_+63)/64, N_), 256, 0, stream>>>(
        htAtt, seq, nullptr, cat + 2*D_,
        P_, D_, C_, C_, D_, D3_,
        (long)P_*C_, (long)C_*D_, (long)P_*D3_, 0);

    // htr = tanh(cat @ We + be)
    k_gemm<<<dim3((D_+63)/64, (NP+63)/64, 1), 256, 0, stream>>>(
        cat, We, be, htr, NP, D_, D3_, D3_, D_, D_, 0, 0, 0, 1);

    // q = htr @ Wq + bq
    k_gemm<<<dim3((D_+63)/64, (NP+63)/64, 1), 256, 0, stream>>>(
        htr, Wq, bq, qb, NP, D_, D_, D_, D_, D_, 0, 0, 0, 0);

    // k = rels @ Wk + bk ; v = rels @ Wv + bv
    k_gemm<<<dim3((D_+63)/64, (R_+63)/64, 1), 256, 0, stream>>>(
        rels, Wk, bk, kb, R_, D_, D_, D_, D_, D_, 0, 0, 0, 0);
    k_gemm<<<dim3((D_+63)/64, (R_+63)/64, 1), 256, 0, stream>>>(
        rels, Wv, bv, vb, R_, D_, D_, D_, D_, D_, 0, 0, 0, 0);

    // attention over rels
    k_attn1<<<NP*H_, 64, 0, stream>>>(qb, kb, vb, o1);

    // self-attention over P
    k_attn2<<<dim3(P_/G2, H_, N_), 256, 0, stream>>>(o1, o2);

    // x = LN(htr + tanh(o2))
    k_ln<<<NP, 256, 0, stream>>>(htr, o2, ln_g, ln_b, xb);

    // logits = x @ Wc + bc
    k_gemm<<<dim3((R_+63)/64, (NP+63)/64, 1), 256, 0, stream>>>(
        xb, Wc, bc, out, NP, R_, D_, D_, R_, R_, 0, 0, 0, 0);
}

// Round 2
// 1128.092 us; speedup vs baseline: 1.3969x; 1.3969x over previous
//
#include <hip/hip_runtime.h>
#include <hip/hip_bf16.h>

#define N_ 4
#define C_ 1024
#define D_ 768
#define H_ 12
#define E_ 24
#define M_ 4
#define P_ 552
#define R_ 97
#define HD_ 64
#define D3_ (3*D_)

#define SCALE_ 0.036084391824351615f  // 1/sqrt(768)

typedef __attribute__((ext_vector_type(8))) short v8s;
typedef __attribute__((ext_vector_type(4))) float v4f;

__device__ inline ushort f2bf(float x) {
    union { float f; unsigned u; } v; v.f = x;
    unsigned r = (v.u + 0x7FFF + ((v.u >> 16) & 1)) >> 16;
    return (ushort)r;
}

// ---------------- K1: ent_emb = logsumexp over M mentions ----------------
__global__ void k_ent_emb(const float* __restrict__ seq, const int* __restrict__ epos,
                          float* __restrict__ entEmb) {
    int idx = blockIdx.x * blockDim.x + threadIdx.x;   // over N*E*D
    if (idx >= N_*E_*D_) return;
    int d  = idx % D_;
    int ne = idx / D_;
    int e  = ne % E_;
    int n  = ne / E_;
    const int* pp = epos + (n*E_ + e)*M_;
    float v[M_];
    float mx = -1e30f;
    #pragma unroll
    for (int m = 0; m < M_; m++) {
        int pos = pp[m] + 1;  // OFFSET
        v[m] = seq[((long)n*C_ + pos)*D_ + d];
        mx = fmaxf(mx, v[m]);
    }
    float s = 0.f;
    #pragma unroll
    for (int m = 0; m < M_; m++) s += expf(v[m] - mx);
    entEmb[idx] = mx + logf(s);
}

// ---------------- K2: ent_att = mean over M of attention rows ----------------
__global__ void k_ent_att(const float* __restrict__ att, const int* __restrict__ epos,
                          float* __restrict__ entAtt) {
    long idx = (long)blockIdx.x * blockDim.x + threadIdx.x;  // over N*E*H*C
    if (idx >= (long)N_*E_*H_*C_) return;
    int c = idx % C_;
    long r = idx / C_;
    int h = r % H_; r /= H_;
    int e = r % E_;
    int n = r / E_;
    const int* pp = epos + (n*E_ + e)*M_;
    float s = 0.f;
    #pragma unroll
    for (int m = 0; m < M_; m++) {
        int pos = pp[m] + 1;
        s += att[(((long)n*H_ + h)*C_ + pos)*C_ + c];
    }
    entAtt[idx] = s * (1.0f / M_);
}

// ---------------- K3: gather hs/ts into bf16 concat buffer ----------------
__global__ void k_gather_ht(const float* __restrict__ entEmb, const int* __restrict__ hts,
                            ushort* __restrict__ bcat) {
    int idx = blockIdx.x * blockDim.x + threadIdx.x;  // over N*P*D
    if (idx >= N_*P_*D_) return;
    int d  = idx % D_;
    int np = idx / D_;
    int p  = np % P_;
    int n  = np / P_;
    int hi = hts[(n*P_ + p)*2 + 0];
    int ti = hts[(n*P_ + p)*2 + 1];
    bcat[(long)np*D3_ + d]       = f2bf(entEmb[((long)n*E_ + hi)*D_ + d]);
    bcat[(long)np*D3_ + D_ + d]  = f2bf(entEmb[((long)n*E_ + ti)*D_ + d]);
}

// ---------------- K4: ht_att (mean over H of h_att*t_att, normalized), bf16 out ----------------
__global__ void k_ht_att(const float* __restrict__ entAtt, const int* __restrict__ hts,
                         ushort* __restrict__ bhtAtt) {
    int np = blockIdx.x;           // N*P blocks
    int p = np % P_, n = np / P_;
    int t = threadIdx.x;           // 256 threads
    int hi = hts[(n*P_ + p)*2 + 0];
    int ti = hts[(n*P_ + p)*2 + 1];
    const float* ha = entAtt + ((long)n*E_ + hi)*H_*C_;
    const float* ta = entAtt + ((long)n*E_ + ti)*H_*C_;
    float vals[C_/256];
    float lsum = 0.f;
    #pragma unroll
    for (int i = 0; i < C_/256; i++) {
        int c = t + i*256;
        float s = 0.f;
        #pragma unroll
        for (int h = 0; h < H_; h++) s += ha[h*C_ + c] * ta[h*C_ + c];
        s *= (1.0f / H_);
        vals[i] = s;
        lsum += s;
    }
    __shared__ float red[256];
    red[t] = lsum; __syncthreads();
    for (int s1 = 128; s1; s1 >>= 1) { if (t < s1) red[t] += red[t+s1]; __syncthreads(); }
    float inv = 1.0f / (red[0] + 1e-5f);
    #pragma unroll
    for (int i = 0; i < C_/256; i++)
        bhtAtt[(long)np*C_ + t + i*256] = f2bf(vals[i] * inv);
}

// ---------------- transpose + cast: X (K x N, f32) -> Xt (N x K, bf16) ----------------
__global__ __launch_bounds__(256) void k_tcast(const float* __restrict__ X, ushort* __restrict__ Xt,
                                               int K, int N, long sX, long sXt) {
    X  += (long)blockIdx.z * sX;
    Xt += (long)blockIdx.z * sXt;
    __shared__ float tile[32][33];
    int t = threadIdx.x;
    int row = t >> 5, col = t & 31;
    int r0 = blockIdx.y * 32, c0 = blockIdx.x * 32;
    #pragma unroll
    for (int i = 0; i < 4; i++) {
        int r = r0 + row + i*8, c = c0 + col;
        tile[row + i*8][col] = (r < K && c < N) ? X[(long)r*N + c] : 0.f;
    }
    __syncthreads();
    #pragma unroll
    for (int i = 0; i < 4; i++) {
        int n = c0 + row + i*8, k = r0 + col;
        if (n < N && k < K) Xt[(long)n*K + k] = f2bf(tile[col][row + i*8]);
    }
}

// ---------------- bf16 MFMA GEMM: C = act(A @ Bt^T + bias) ----------------
// A: M x K bf16 row-major (lda). Bt: N x K bf16 row-major (ldb). K % 32 == 0.
// Tile 128x128, BK=32, 256 threads (4 waves), each wave 64x64 via 4x4 mfma 16x16x32.
// Outputs: Cf (f32, ldcf) and/or Cb (bf16, ldcb). act=1 -> tanh.
__global__ __launch_bounds__(256) void k_mfma_bt(
        const ushort* __restrict__ A, const ushort* __restrict__ Bt,
        const float* __restrict__ bias, float* __restrict__ Cf, ushort* __restrict__ Cb,
        int M, int N, int K, int lda, int ldb, int ldcf, int ldcb,
        long sA, long sB, long sCf, long sCb, int act) {
    int batch = blockIdx.z;
    A  += (long)batch * sA;
    Bt += (long)batch * sB;
    __shared__ ushort As[128*32];
    __shared__ ushort Bs[128*32];
    int t = threadIdx.x;
    int m0 = blockIdx.y * 128, n0 = blockIdx.x * 128;
    int lr = t >> 2;            // 0..63
    int lc = (t & 3) * 8;       // 0,8,16,24
    int wv = t >> 6, lane = t & 63;
    int quad = lane >> 4, lm = lane & 15;
    int wm = (wv >> 1) * 64, wn = (wv & 1) * 64;

    v4f acc[4][4];
    #pragma unroll
    for (int i = 0; i < 4; i++)
        #pragma unroll
        for (int j = 0; j < 4; j++)
            acc[i][j] = (v4f){0.f, 0.f, 0.f, 0.f};

    const uint4 zero4 = {0u,0u,0u,0u};
    for (int k0 = 0; k0 < K; k0 += 32) {
        // stage A: rows lr, lr+64
        #pragma unroll
        for (int half = 0; half < 2; half++) {
            int row = lr + half*64;
            int gm = m0 + row;
            uint4 val = zero4;
            if (gm < M) val = *(const uint4*)(A + (long)gm*lda + k0 + lc);
            *(uint4*)(&As[row*32 + lc]) = val;
        }
        // stage Bt: rows lr, lr+64
        #pragma unroll
        for (int half = 0; half < 2; half++) {
            int row = lr + half*64;
            int gn = n0 + row;
            uint4 val = zero4;
            if (gn < N) val = *(const uint4*)(Bt + (long)gn*ldb + k0 + lc);
            *(uint4*)(&Bs[row*32 + lc]) = val;
        }
        __syncthreads();
        v8s a[4], b[4];
        #pragma unroll
        for (int i = 0; i < 4; i++)
            a[i] = *(const v8s*)(&As[(wm + i*16 + lm)*32 + quad*8]);
        #pragma unroll
        for (int j = 0; j < 4; j++)
            b[j] = *(const v8s*)(&Bs[(wn + j*16 + lm)*32 + quad*8]);
        #pragma unroll
        for (int i = 0; i < 4; i++)
            #pragma unroll
            for (int j = 0; j < 4; j++)
                acc[i][j] = __builtin_amdgcn_mfma_f32_16x16x32_bf16(a[i], b[j], acc[i][j], 0, 0, 0);
        __syncthreads();
    }

    // epilogue: C/D layout col=lane&15, row=quad*4+reg
    #pragma unroll
    for (int j = 0; j < 4; j++) {
        int gn = n0 + wn + j*16 + lm;
        if (gn >= N) continue;
        float bv = bias ? bias[gn] : 0.f;
        #pragma unroll
        for (int i = 0; i < 4; i++) {
            #pragma unroll
            for (int reg = 0; reg < 4; reg++) {
                int gm = m0 + wm + i*16 + quad*4 + reg;
                if (gm >= M) continue;
                float v = acc[i][j][reg] + bv;
                if (act == 1) v = tanhf(v);
                if (Cf) Cf[(long)batch*sCf + (long)gm*ldcf + gn] = v;
                if (Cb) Cb[(long)batch*sCb + (long)gm*ldcb + gn] = f2bf(v);
            }
        }
    }
}

// ---------------- small f32 GEMM (kept for rels @ Wk/Wv) ----------------
__global__ __launch_bounds__(256) void k_gemm(
        const float* __restrict__ A, const float* __restrict__ B,
        const float* __restrict__ bias, float* __restrict__ C,
        int M, int N, int K, int lda, int ldb, int ldc,
        long sA, long sB, long sC, int act) {
    int batch = blockIdx.z;
    A += (long)batch * sA; B += (long)batch * sB; C += (long)batch * sC;
    __shared__ float As[16][64+1];
    __shared__ float Bs[16][64];
    int t = threadIdx.x;
    int m0 = blockIdx.y * 64, n0 = blockIdx.x * 64;
    int tm = t >> 4, tn = t & 15;
    float acc[4][4] = {};
    int kkA = t & 15, mA = t >> 4;
    int nnB = t & 63, kB = t >> 6;
    for (int k0 = 0; k0 < K; k0 += 16) {
        #pragma unroll
        for (int i = 0; i < 4; i++) {
            int m = mA + i*16;
            int gm = m0 + m;
            As[kkA][m] = (gm < M) ? A[(long)gm*lda + k0 + kkA] : 0.f;
        }
        #pragma unroll
        for (int i = 0; i < 4; i++) {
            int kkb = kB + i*4;
            int gn = n0 + nnB;
            Bs[kkb][nnB] = (gn < N) ? B[(long)(k0+kkb)*ldb + gn] : 0.f;
        }
        __syncthreads();
        #pragma unroll
        for (int kk = 0; kk < 16; kk++) {
            float a[4], b[4];
            #pragma unroll
            for (int i = 0; i < 4; i++) a[i] = As[kk][tm*4+i];
            #pragma unroll
            for (int j = 0; j < 4; j++) b[j] = Bs[kk][tn*4+j];
            #pragma unroll
            for (int i = 0; i < 4; i++)
                #pragma unroll
                for (int j = 0; j < 4; j++)
                    acc[i][j] += a[i]*b[j];
        }
        __syncthreads();
    }
    #pragma unroll
    for (int i = 0; i < 4; i++) {
        int gm = m0 + tm*4 + i;
        if (gm >= M) continue;
        #pragma unroll
        for (int j = 0; j < 4; j++) {
            int gn = n0 + tn*4 + j;
            if (gn >= N) continue;
            float v = acc[i][j] + (bias ? bias[gn] : 0.f);
            if (act == 1) v = tanhf(v);
            C[(long)gm*ldc + gn] = v;
        }
    }
}

// ---------------- attention over R=97 rels, fused (one wave per (np,h)) ----------------
__global__ void k_attn1(const float* __restrict__ qb, const float* __restrict__ kb,
                        const float* __restrict__ vb, float* __restrict__ o1) {
    int b = blockIdx.x;            // N*P*H blocks, 64 threads
    int h = b % H_;
    int np = b / H_;
    int lane = threadIdx.x;
    __shared__ float qs[64];
    __shared__ float wsm[128];
    qs[lane] = qb[(long)np*D_ + h*HD_ + lane];
    __syncthreads();
    float s0, s1 = -1e30f;
    {
        const float* kr = kb + (long)lane*D_ + h*HD_;
        float acc = 0.f;
        #pragma unroll
        for (int e = 0; e < 64; e++) acc += qs[e]*kr[e];
        s0 = acc * SCALE_;
    }
    if (lane + 64 < R_) {
        const float* kr = kb + (long)(lane+64)*D_ + h*HD_;
        float acc = 0.f;
        #pragma unroll
        for (int e = 0; e < 64; e++) acc += qs[e]*kr[e];
        s1 = acc * SCALE_;
    }
    float m = fmaxf(s0, s1);
    for (int off = 32; off; off >>= 1) m = fmaxf(m, __shfl_xor(m, off));
    float w0 = expf(s0 - m);
    float w1 = (lane + 64 < R_) ? expf(s1 - m) : 0.f;
    float ls = w0 + w1;
    for (int off = 32; off; off >>= 1) ls += __shfl_xor(ls, off);
    wsm[lane] = w0; wsm[64+lane] = w1;
    __syncthreads();
    float inv_l = 1.0f / ls;
    float acc = 0.f;
    for (int r = 0; r < R_; r++)
        acc += wsm[r] * vb[(long)r*D_ + h*HD_ + lane];
    o1[(long)np*D_ + h*HD_ + lane] = acc * inv_l;
}

// ---------------- self-attention over P=552 (scores2), fused, 8 queries/block ----------------
#define G2 8
__global__ __launch_bounds__(256) void k_attn2(const float* __restrict__ o1, float* __restrict__ o2) {
    int pt = blockIdx.x;   // 0..P/G2-1
    int h  = blockIdx.y;
    int n  = blockIdx.z;
    int p0 = pt * G2;
    int t = threadIdx.x;
    const float* base = o1 + (long)n*P_*D_ + h*HD_;
    __shared__ float opS[G2][HD_];
    __shared__ float sArr[G2][P_];
    __shared__ float lS[G2];
    __shared__ float accS[4][G2][HD_];
    for (int i = t; i < G2*HD_; i += 256) {
        int pi = i / HD_, e = i % HD_;
        opS[pi][e] = base[(long)(p0+pi)*D_ + e];
    }
    __syncthreads();
    for (int q = t; q < P_; q += 256) {
        const float* row = base + (long)q*D_;
        float acc[G2];
        #pragma unroll
        for (int pi = 0; pi < G2; pi++) acc[pi] = 0.f;
        for (int e = 0; e < HD_; e++) {
            float rv = row[e];
            #pragma unroll
            for (int pi = 0; pi < G2; pi++) acc[pi] += opS[pi][e]*rv;
        }
        #pragma unroll
        for (int pi = 0; pi < G2; pi++) sArr[pi][q] = acc[pi]*SCALE_;
    }
    __syncthreads();
    int wv = t >> 6, lane = t & 63;
    for (int pi = wv*2; pi < wv*2+2; pi++) {
        float m = -1e30f;
        for (int q = lane; q < P_; q += 64) m = fmaxf(m, sArr[pi][q]);
        for (int off = 32; off; off >>= 1) m = fmaxf(m, __shfl_xor(m, off));
        float ls = 0.f;
        for (int q = lane; q < P_; q += 64) {
            float w = expf(sArr[pi][q] - m);
            sArr[pi][q] = w;
            ls += w;
        }
        for (int off = 32; off; off >>= 1) ls += __shfl_xor(ls, off);
        if (lane == 0) lS[pi] = ls;
    }
    __syncthreads();
    int e = t & 63, g = t >> 6;
    float acc[G2];
    #pragma unroll
    for (int pi = 0; pi < G2; pi++) acc[pi] = 0.f;
    for (int q = g; q < P_; q += 4) {
        float rv = base[(long)q*D_ + e];
        #pragma unroll
        for (int pi = 0; pi < G2; pi++) acc[pi] += sArr[pi][q]*rv;
    }
    #pragma unroll
    for (int pi = 0; pi < G2; pi++) accS[g][pi][e] = acc[pi];
    __syncthreads();
    for (int i = t; i < G2*HD_; i += 256) {
        int pi = i / HD_, e2 = i % HD_;
        float v = (accS[0][pi][e2]+accS[1][pi][e2]+accS[2][pi][e2]+accS[3][pi][e2]) / lS[pi];
        o2[((long)n*P_ + p0+pi)*D_ + h*HD_ + e2] = v;
    }
}

// ---------------- x = LN(htr + tanh(o2)) -> bf16 ----------------
__global__ void k_ln(const float* __restrict__ htr, const float* __restrict__ o2,
                     const float* __restrict__ g, const float* __restrict__ b,
                     ushort* __restrict__ bx) {
    int np = blockIdx.x;    // N*P blocks
    int t = threadIdx.x;    // 256 threads
    __shared__ float red[256];
    float v[D_/256];
    float s = 0.f;
    #pragma unroll
    for (int i = 0; i < D_/256; i++) {
        int d = t + i*256;
        float val = htr[(long)np*D_ + d] + tanhf(o2[(long)np*D_ + d]);
        v[i] = val; s += val;
    }
    red[t] = s; __syncthreads();
    for (int s1 = 128; s1; s1 >>= 1) { if (t < s1) red[t] += red[t+s1]; __syncthreads(); }
    float mu = red[0] * (1.0f/D_);
    __syncthreads();
    float s2 = 0.f;
    #pragma unroll
    for (int i = 0; i < D_/256; i++) { float dx = v[i]-mu; s2 += dx*dx; }
    red[t] = s2; __syncthreads();
    for (int s1 = 128; s1; s1 >>= 1) { if (t < s1) red[t] += red[t+s1]; __syncthreads(); }
    float inv = rsqrtf(red[0]*(1.0f/D_) + 1e-5f);
    #pragma unroll
    for (int i = 0; i < D_/256; i++) {
        int d = t + i*256;
        bx[(long)np*D_ + d] = f2bf((v[i]-mu)*inv*g[d] + b[d]);
    }
}

extern "C" void kernel_launch(void* const* d_in, const int* in_sizes, int n_in,
                              void* d_out, int out_size, void* d_ws, size_t ws_size,
                              hipStream_t stream) {
    const float* seq   = (const float*)d_in[0];
    const float* att   = (const float*)d_in[1];
    const int*   epos  = (const int*)d_in[2];
    const int*   hts   = (const int*)d_in[3];
    const float* rels  = (const float*)d_in[4];
    const float* We    = (const float*)d_in[5];
    const float* be    = (const float*)d_in[6];
    const float* Wq    = (const float*)d_in[7];
    const float* bq    = (const float*)d_in[8];
    const float* Wk    = (const float*)d_in[9];
    const float* bk    = (const float*)d_in[10];
    const float* Wv    = (const float*)d_in[11];
    const float* bv    = (const float*)d_in[12];
    const float* ln_g  = (const float*)d_in[13];
    const float* ln_b  = (const float*)d_in[14];
    const float* Wc    = (const float*)d_in[15];
    const float* bc    = (const float*)d_in[16];
    float* out = (float*)d_out;
    float* w = (float*)d_ws;

    const int NP = N_*P_;  // 2208

    // f32 workspace
    float* entEmb = w;                              // 73,728
    float* entAtt = entEmb + (size_t)N_*E_*D_;      // 1,179,648
    float* htr    = entAtt + (size_t)N_*E_*H_*C_;   // 1,695,744
    float* qb     = htr    + (size_t)NP*D_;         // 1,695,744
    float* kb     = qb     + (size_t)NP*D_;         // 74,496
    float* vb     = kb     + (size_t)R_*D_;         // 74,496
    float* o1     = vb     + (size_t)R_*D_;         // 1,695,744
    float* o2     = o1     + (size_t)NP*D_;         // 1,695,744
    // bf16 workspace
    ushort* bhtAtt = (ushort*)(o2 + (size_t)NP*D_); // 2,260,992
    ushort* bcat   = bhtAtt + (size_t)NP*C_;        // 5,087,232
    ushort* bhtr   = bcat   + (size_t)NP*D3_;       // 1,695,744
    ushort* bxb    = bhtr   + (size_t)NP*D_;        // 1,695,744
    ushort* seqT   = bxb    + (size_t)NP*D_;        // 3,145,728
    ushort* WeT    = seqT   + (size_t)N_*D_*C_;     // 1,769,472
    ushort* WqT    = WeT    + (size_t)D_*D3_;       // 589,824
    ushort* WcT    = WqT    + (size_t)D_*D_;        // 74,496

    // operand transposes/casts (only read inputs)
    k_tcast<<<dim3(24, 32, N_), 256, 0, stream>>>(seq, seqT, C_, D_, (long)C_*D_, (long)D_*C_);
    k_tcast<<<dim3(24, 72, 1), 256, 0, stream>>>(We, WeT, D3_, D_, 0, 0);
    k_tcast<<<dim3(24, 24, 1), 256, 0, stream>>>(Wq, WqT, D_, D_, 0, 0);
    k_tcast<<<dim3(4, 24, 1), 256, 0, stream>>>(Wc, WcT, D_, R_, 0, 0);

    k_ent_emb<<<(N_*E_*D_+255)/256, 256, 0, stream>>>(seq, epos, entEmb);
    k_ent_att<<<(N_*E_*H_*C_+255)/256, 256, 0, stream>>>(att, epos, entAtt);
    k_gather_ht<<<(N_*P_*D_+255)/256, 256, 0, stream>>>(entEmb, hts, bcat);
    k_ht_att<<<NP, 256, 0, stream>>>(entAtt, hts, bhtAtt);

    // rs = batched bhtAtt(n) @ seqT(n)^T -> bcat[:, 2D:3D] (bf16)
    k_mfma_bt<<<dim3(6, 5, N_), 256, 0, stream>>>(
        bhtAtt, seqT, nullptr, nullptr, bcat + 2*D_,
        P_, D_, C_, C_, C_, 0, D3_,
        (long)P_*C_, (long)D_*C_, 0, (long)P_*D3_, 0);

    // htr = tanh(bcat @ WeT^T + be) -> f32 htr AND bf16 bhtr
    k_mfma_bt<<<dim3(6, 18, 1), 256, 0, stream>>>(
        bcat, WeT, be, htr, bhtr,
        NP, D_, D3_, D3_, D3_, D_, D_,
        0, 0, 0, 0, 1);

    // q = bhtr @ WqT^T + bq -> f32
    k_mfma_bt<<<dim3(6, 18, 1), 256, 0, stream>>>(
        bhtr, WqT, bq, qb, nullptr,
        NP, D_, D_, D_, D_, D_, 0,
        0, 0, 0, 0, 0);

    // k = rels @ Wk + bk ; v = rels @ Wv + bv (small, f32)
    k_gemm<<<dim3((D_+63)/64, (R_+63)/64, 1), 256, 0, stream>>>(
        rels, Wk, bk, kb, R_, D_, D_, D_, D_, D_, 0, 0, 0, 0);
    k_gemm<<<dim3((D_+63)/64, (R_+63)/64, 1), 256, 0, stream>>>(
        rels, Wv, bv, vb, R_, D_, D_, D_, D_, D_, 0, 0, 0, 0);

    // attention over rels
    k_attn1<<<NP*H_, 64, 0, stream>>>(qb, kb, vb, o1);

    // self-attention over P
    k_attn2<<<dim3(P_/G2, H_, N_), 256, 0, stream>>>(o1, o2);

    // x = LN(htr + tanh(o2)) -> bf16
    k_ln<<<NP, 256, 0, stream>>>(htr, o2, ln_g, ln_b, bxb);

    // logits = bxb @ WcT^T + bc -> f32 out
    k_mfma_bt<<<dim3(1, 18, 1), 256, 0, stream>>>(
        bxb, WcT, bc, out, nullptr,
        NP, R_, D_, D_, D_, R_, 0,
        0, 0, 0, 0, 0);
}

// Round 3
// 763.565 us; speedup vs baseline: 2.0638x; 1.4774x over previous
//
#include <hip/hip_runtime.h>
#include <hip/hip_bf16.h>

#define N_ 4
#define C_ 1024
#define D_ 768
#define H_ 12
#define E_ 24
#define M_ 4
#define P_ 552
#define R_ 97
#define HD_ 64
#define D3_ (3*D_)

#define SCALE_ 0.036084391824351615f  // 1/sqrt(768)

typedef __attribute__((ext_vector_type(8))) short v8s;
typedef __attribute__((ext_vector_type(4))) float v4f;

__device__ inline ushort f2bf(float x) {
    union { float f; unsigned u; } v; v.f = x;
    unsigned r = (v.u + 0x7FFF + ((v.u >> 16) & 1)) >> 16;
    return (ushort)r;
}
__device__ inline float bf2f(ushort x) {
    union { float f; unsigned u; } v; v.u = ((unsigned)x) << 16;
    return v.f;
}

// ---------------- K1: ent_emb = logsumexp over M mentions ----------------
__global__ void k_ent_emb(const float* __restrict__ seq, const int* __restrict__ epos,
                          float* __restrict__ entEmb) {
    int idx = blockIdx.x * blockDim.x + threadIdx.x;   // over N*E*D
    if (idx >= N_*E_*D_) return;
    int d  = idx % D_;
    int ne = idx / D_;
    int e  = ne % E_;
    int n  = ne / E_;
    const int* pp = epos + (n*E_ + e)*M_;
    float v[M_];
    float mx = -1e30f;
    #pragma unroll
    for (int m = 0; m < M_; m++) {
        int pos = pp[m] + 1;  // OFFSET
        v[m] = seq[((long)n*C_ + pos)*D_ + d];
        mx = fmaxf(mx, v[m]);
    }
    float s = 0.f;
    #pragma unroll
    for (int m = 0; m < M_; m++) s += expf(v[m] - mx);
    entEmb[idx] = mx + logf(s);
}

// ---------------- K2: ent_att = mean over M of attention rows ----------------
__global__ void k_ent_att(const float* __restrict__ att, const int* __restrict__ epos,
                          float* __restrict__ entAtt) {
    long idx = (long)blockIdx.x * blockDim.x + threadIdx.x;  // over N*E*H*C
    if (idx >= (long)N_*E_*H_*C_) return;
    int c = idx % C_;
    long r = idx / C_;
    int h = r % H_; r /= H_;
    int e = r % E_;
    int n = r / E_;
    const int* pp = epos + (n*E_ + e)*M_;
    float s = 0.f;
    #pragma unroll
    for (int m = 0; m < M_; m++) {
        int pos = pp[m] + 1;
        s += att[(((long)n*H_ + h)*C_ + pos)*C_ + c];
    }
    entAtt[idx] = s * (1.0f / M_);
}

// ---------------- K3: gather hs/ts into bf16 concat buffer ----------------
__global__ void k_gather_ht(const float* __restrict__ entEmb, const int* __restrict__ hts,
                            ushort* __restrict__ bcat) {
    int idx = blockIdx.x * blockDim.x + threadIdx.x;  // over N*P*D
    if (idx >= N_*P_*D_) return;
    int d  = idx % D_;
    int np = idx / D_;
    int p  = np % P_;
    int n  = np / P_;
    int hi = hts[(n*P_ + p)*2 + 0];
    int ti = hts[(n*P_ + p)*2 + 1];
    bcat[(long)np*D3_ + d]       = f2bf(entEmb[((long)n*E_ + hi)*D_ + d]);
    bcat[(long)np*D3_ + D_ + d]  = f2bf(entEmb[((long)n*E_ + ti)*D_ + d]);
}

// ---------------- K4: ht_att (mean over H of h_att*t_att, normalized), bf16 out ----------------
__global__ void k_ht_att(const float* __restrict__ entAtt, const int* __restrict__ hts,
                         ushort* __restrict__ bhtAtt) {
    int np = blockIdx.x;           // N*P blocks
    int p = np % P_, n = np / P_;
    int t = threadIdx.x;           // 256 threads
    int hi = hts[(n*P_ + p)*2 + 0];
    int ti = hts[(n*P_ + p)*2 + 1];
    const float* ha = entAtt + ((long)n*E_ + hi)*H_*C_;
    const float* ta = entAtt + ((long)n*E_ + ti)*H_*C_;
    float vals[C_/256];
    float lsum = 0.f;
    #pragma unroll
    for (int i = 0; i < C_/256; i++) {
        int c = t + i*256;
        float s = 0.f;
        #pragma unroll
        for (int h = 0; h < H_; h++) s += ha[h*C_ + c] * ta[h*C_ + c];
        s *= (1.0f / H_);
        vals[i] = s;
        lsum += s;
    }
    __shared__ float red[256];
    red[t] = lsum; __syncthreads();
    for (int s1 = 128; s1; s1 >>= 1) { if (t < s1) red[t] += red[t+s1]; __syncthreads(); }
    float inv = 1.0f / (red[0] + 1e-5f);
    #pragma unroll
    for (int i = 0; i < C_/256; i++)
        bhtAtt[(long)np*C_ + t + i*256] = f2bf(vals[i] * inv);
}

// ---------------- transpose + cast: X (K x N, f32) -> Xt (N x K, bf16) ----------------
__global__ __launch_bounds__(256) void k_tcast(const float* __restrict__ X, ushort* __restrict__ Xt,
                                               int K, int N, long sX, long sXt) {
    X  += (long)blockIdx.z * sX;
    Xt += (long)blockIdx.z * sXt;
    __shared__ float tile[32][33];
    int t = threadIdx.x;
    int row = t >> 5, col = t & 31;
    int r0 = blockIdx.y * 32, c0 = blockIdx.x * 32;
    #pragma unroll
    for (int i = 0; i < 4; i++) {
        int r = r0 + row + i*8, c = c0 + col;
        tile[row + i*8][col] = (r < K && c < N) ? X[(long)r*N + c] : 0.f;
    }
    __syncthreads();
    #pragma unroll
    for (int i = 0; i < 4; i++) {
        int n = c0 + row + i*8, k = r0 + col;
        if (n < N && k < K) Xt[(long)n*K + k] = f2bf(tile[col][row + i*8]);
    }
}

// ---------------- elementwise cast f32 -> bf16 ----------------
__global__ void k_cast(const float* __restrict__ x, ushort* __restrict__ y, int n) {
    int i = blockIdx.x * blockDim.x + threadIdx.x;
    if (i < n) y[i] = f2bf(x[i]);
}

// ---------------- generalized bf16 MFMA GEMM: C = act(A @ Bt^T + bias) ----------------
// A: M x K bf16 (lda). Bt: N x K bf16 (ldb). K % 32 == 0, all K-offsets 16B-aligned.
// batch z: b1 = z/nb2, b2 = z%nb2; A += b1*sA1+b2*sA2 etc.
// Writes cols gn < Npad: value = (gn<N) ? act(acc+bias) : 0.
__global__ __launch_bounds__(256) void k_mfma_bt(
        const ushort* __restrict__ A, const ushort* __restrict__ Bt,
        const float* __restrict__ bias, float* __restrict__ Cf, ushort* __restrict__ Cb,
        int M, int N, int Npad, int K,
        int lda, int ldb, int ldcf, int ldcb, int nb2,
        long sA1, long sA2, long sB1, long sB2,
        long sCf1, long sCf2, long sCb1, long sCb2,
        int act, int biasM) {
    int z = blockIdx.z;
    int b1 = z / nb2, b2 = z % nb2;
    A  += b1*sA1 + b2*sA2;
    Bt += b1*sB1 + b2*sB2;
    long cfo = b1*sCf1 + b2*sCf2;
    long cbo = b1*sCb1 + b2*sCb2;
    __shared__ ushort As[128*32];
    __shared__ ushort Bs[128*32];
    int t = threadIdx.x;
    int m0 = blockIdx.y * 128, n0 = blockIdx.x * 128;
    int lr = t >> 2;            // 0..63
    int lc = (t & 3) * 8;       // 0,8,16,24
    int wv = t >> 6, lane = t & 63;
    int quad = lane >> 4, lm = lane & 15;
    int wm = (wv >> 1) * 64, wn = (wv & 1) * 64;

    v4f acc[4][4];
    #pragma unroll
    for (int i = 0; i < 4; i++)
        #pragma unroll
        for (int j = 0; j < 4; j++)
            acc[i][j] = (v4f){0.f, 0.f, 0.f, 0.f};

    const uint4 zero4 = {0u,0u,0u,0u};
    for (int k0 = 0; k0 < K; k0 += 32) {
        #pragma unroll
        for (int half = 0; half < 2; half++) {
            int row = lr + half*64;
            int gm = m0 + row;
            uint4 val = zero4;
            if (gm < M) val = *(const uint4*)(A + (long)gm*lda + k0 + lc);
            *(uint4*)(&As[row*32 + lc]) = val;
        }
        #pragma unroll
        for (int half = 0; half < 2; half++) {
            int row = lr + half*64;
            int gn = n0 + row;
            uint4 val = zero4;
            if (gn < N) val = *(const uint4*)(Bt + (long)gn*ldb + k0 + lc);
            *(uint4*)(&Bs[row*32 + lc]) = val;
        }
        __syncthreads();
        v8s a[4], b[4];
        #pragma unroll
        for (int i = 0; i < 4; i++)
            a[i] = *(const v8s*)(&As[(wm + i*16 + lm)*32 + quad*8]);
        #pragma unroll
        for (int j = 0; j < 4; j++)
            b[j] = *(const v8s*)(&Bs[(wn + j*16 + lm)*32 + quad*8]);
        #pragma unroll
        for (int i = 0; i < 4; i++)
            #pragma unroll
            for (int j = 0; j < 4; j++)
                acc[i][j] = __builtin_amdgcn_mfma_f32_16x16x32_bf16(a[i], b[j], acc[i][j], 0, 0, 0);
        __syncthreads();
    }

    // epilogue: C/D layout col=lane&15, row=quad*4+reg
    #pragma unroll
    for (int j = 0; j < 4; j++) {
        int gn = n0 + wn + j*16 + lm;
        if (gn >= Npad) continue;
        bool vld = gn < N;
        float bvn = (bias && !biasM && vld) ? bias[gn] : 0.f;
        #pragma unroll
        for (int i = 0; i < 4; i++) {
            #pragma unroll
            for (int reg = 0; reg < 4; reg++) {
                int gm = m0 + wm + i*16 + quad*4 + reg;
                if (gm >= M) continue;
                float v = 0.f;
                if (vld) {
                    v = acc[i][j][reg] + bvn;
                    if (bias && biasM) v += bias[gm];
                    if (act == 1) v = tanhf(v);
                }
                if (Cf) Cf[cfo + (long)gm*ldcf + gn] = v;
                if (Cb) Cb[cbo + (long)gm*ldcb + gn] = f2bf(v);
            }
        }
    }
}

// ---------------- softmax over scores1: rows of 97 (f32, ld 128) -> bf16 P1 (ld 128, zero-pad) --
__global__ void k_softmax1(const float* __restrict__ S, ushort* __restrict__ P) {
    int row = blockIdx.x*4 + (threadIdx.x >> 6);   // 26496 rows total
    int lane = threadIdx.x & 63;
    const float* r = S + (long)row*128;
    float v0 = r[lane] * SCALE_;
    float v1 = (lane + 64 < R_) ? r[lane+64] * SCALE_ : -1e30f;
    float m = fmaxf(v0, v1);
    for (int o = 32; o; o >>= 1) m = fmaxf(m, __shfl_xor(m, o));
    float e0 = expf(v0 - m);
    float e1 = (lane + 64 < R_) ? expf(v1 - m) : 0.f;
    float s = e0 + e1;
    for (int o = 32; o; o >>= 1) s += __shfl_xor(s, o);
    float inv = 1.0f / s;
    ushort* pr = P + (long)row*128;
    pr[lane]      = f2bf(e0 * inv);
    pr[lane + 64] = f2bf(e1 * inv);
}

// ---------------- softmax over scores2: in-place bf16 rows of 552 (ld 576, zero-pad) ------------
__global__ void k_softmax2(ushort* __restrict__ S) {
    int row = blockIdx.x*4 + (threadIdx.x >> 6);   // 26496 rows total
    int lane = threadIdx.x & 63;
    ushort* r = S + (long)row*576;
    float v[9];
    float m = -1e30f;
    #pragma unroll
    for (int i = 0; i < 9; i++) {
        int col = lane + i*64;
        if (col < P_) { v[i] = bf2f(r[col]) * SCALE_; m = fmaxf(m, v[i]); }
        else v[i] = -1e30f;
    }
    for (int o = 32; o; o >>= 1) m = fmaxf(m, __shfl_xor(m, o));
    float s = 0.f;
    float e[9];
    #pragma unroll
    for (int i = 0; i < 9; i++) {
        int col = lane + i*64;
        e[i] = (col < P_) ? expf(v[i] - m) : 0.f;
        s += e[i];
    }
    for (int o = 32; o; o >>= 1) s += __shfl_xor(s, o);
    float inv = 1.0f / s;
    #pragma unroll
    for (int i = 0; i < 9; i++) {
        int col = lane + i*64;
        r[col] = f2bf(e[i] * inv);
    }
}

// ---------------- o1T: per (n,h) transpose o1b (552x64 slice) -> (64 x 576, zero-pad q) --------
__global__ __launch_bounds__(256) void k_o1t(const ushort* __restrict__ o1b, ushort* __restrict__ o1T) {
    int z = blockIdx.z; int n = z / H_, h = z % H_;
    int qt = blockIdx.x;   // 18 tiles over q (576)
    int et = blockIdx.y;   // 2 tiles over e (64)
    __shared__ ushort tile[32][33];
    int t = threadIdx.x; int row = t >> 5, col = t & 31;
    const ushort* src = o1b + (long)n*P_*D_ + h*HD_;
    #pragma unroll
    for (int i = 0; i < 4; i++) {
        int q = qt*32 + row + i*8, e = et*32 + col;
        tile[row + i*8][col] = (q < P_) ? src[(long)q*D_ + e] : (ushort)0;
    }
    __syncthreads();
    ushort* dst = o1T + (long)z*HD_*576;
    #pragma unroll
    for (int i = 0; i < 4; i++) {
        int e = et*32 + row + i*8, q = qt*32 + col;
        dst[(long)e*576 + q] = tile[col][row + i*8];
    }
}

// ---------------- x = LN(htr + tanh(o2)) -> bf16 ----------------
__global__ void k_ln(const float* __restrict__ htr, const float* __restrict__ o2,
                     const float* __restrict__ g, const float* __restrict__ b,
                     ushort* __restrict__ bx) {
    int np = blockIdx.x;    // N*P blocks
    int t = threadIdx.x;    // 256 threads
    __shared__ float red[256];
    float v[D_/256];
    float s = 0.f;
    #pragma unroll
    for (int i = 0; i < D_/256; i++) {
        int d = t + i*256;
        float val = htr[(long)np*D_ + d] + tanhf(o2[(long)np*D_ + d]);
        v[i] = val; s += val;
    }
    red[t] = s; __syncthreads();
    for (int s1 = 128; s1; s1 >>= 1) { if (t < s1) red[t] += red[t+s1]; __syncthreads(); }
    float mu = red[0] * (1.0f/D_);
    __syncthreads();
    float s2 = 0.f;
    #pragma unroll
    for (int i = 0; i < D_/256; i++) { float dx = v[i]-mu; s2 += dx*dx; }
    red[t] = s2; __syncthreads();
    for (int s1 = 128; s1; s1 >>= 1) { if (t < s1) red[t] += red[t+s1]; __syncthreads(); }
    float inv = rsqrtf(red[0]*(1.0f/D_) + 1e-5f);
    #pragma unroll
    for (int i = 0; i < D_/256; i++) {
        int d = t + i*256;
        bx[(long)np*D_ + d] = f2bf((v[i]-mu)*inv*g[d] + b[d]);
    }
}

extern "C" void kernel_launch(void* const* d_in, const int* in_sizes, int n_in,
                              void* d_out, int out_size, void* d_ws, size_t ws_size,
                              hipStream_t stream) {
    const float* seq   = (const float*)d_in[0];
    const float* att   = (const float*)d_in[1];
    const int*   epos  = (const int*)d_in[2];
    const int*   hts   = (const int*)d_in[3];
    const float* rels  = (const float*)d_in[4];
    const float* We    = (const float*)d_in[5];
    const float* be    = (const float*)d_in[6];
    const float* Wq    = (const float*)d_in[7];
    const float* bq    = (const float*)d_in[8];
    const float* Wk    = (const float*)d_in[9];
    const float* bk    = (const float*)d_in[10];
    const float* Wv    = (const float*)d_in[11];
    const float* bv    = (const float*)d_in[12];
    const float* ln_g  = (const float*)d_in[13];
    const float* ln_b  = (const float*)d_in[14];
    const float* Wc    = (const float*)d_in[15];
    const float* bc    = (const float*)d_in[16];
    float* out = (float*)d_out;
    float* w = (float*)d_ws;

    const int NP = N_*P_;  // 2208

    // ---- f32 workspace ----
    float* entEmb  = w;                                 //    73,728
    float* entAtt  = entEmb  + (size_t)N_*E_*D_;        // 1,179,648
    float* htr     = entAtt  + (size_t)N_*E_*H_*C_;     // 1,695,744
    float* o2      = htr     + (size_t)NP*D_;           // 1,695,744
    float* scores1 = o2      + (size_t)NP*D_;           // 3,391,488 (NP*12*? no: NP rows per head) -> NP*128 per head * 12
    // scores1 layout: [h][np][128] = 12 * 2208 * 128 = 3,391,488 floats
    // ---- bf16 workspace ----
    ushort* bhtAtt = (ushort*)(scores1 + (size_t)H_*NP*128);   // 2,260,992
    // REGION: union of early-dead buffers and s2 (which needs 15,261,696 ushorts)
    ushort* region = bhtAtt + (size_t)NP*C_;
    ushort* bcat   = region;                       // 5,087,232
    ushort* seqT   = bcat  + (size_t)NP*D3_;       // 3,145,728
    ushort* WeT    = seqT  + (size_t)N_*D_*C_;     // 1,769,472
    ushort* WqT    = WeT   + (size_t)D_*D3_;       //   589,824
    ushort* WkT    = WqT   + (size_t)D_*D_;        //   589,824
    ushort* WvT    = WkT   + (size_t)D_*D_;        //   589,824
    ushort* bqb    = WvT   + (size_t)D_*D_;        // 1,695,744
    ushort* P1     = bqb   + (size_t)NP*D_;        // 3,391,488
    ushort* s2     = region;                       // 15,261,696 (aliases all of the above region)
    ushort* after  = region + 16859136;            // region size = sum above
    ushort* bhtr   = after;                        // 1,695,744
    ushort* bxb    = bhtr  + (size_t)NP*D_;        // 1,695,744
    ushort* WcT    = bxb   + (size_t)NP*D_;        //    74,496
    ushort* relsB  = WcT   + (size_t)D_*R_;        //    74,496
    ushort* bkb    = relsB + (size_t)R_*D_;        //    74,496
    ushort* vT     = bkb   + (size_t)R_*D_;        //    98,304 (768 x 128)
    ushort* o1b    = vT    + (size_t)D_*128;       // 1,695,744
    ushort* o1T    = o1b   + (size_t)NP*D_;        // 1,769,472 (48 x 64 x 576)

    // ---- operand transposes / casts ----
    k_tcast<<<dim3(24, 32, N_), 256, 0, stream>>>(seq, seqT, C_, D_, (long)C_*D_, (long)D_*C_);
    k_tcast<<<dim3(24, 72, 1), 256, 0, stream>>>(We, WeT, D3_, D_, 0, 0);
    k_tcast<<<dim3(24, 24, 1), 256, 0, stream>>>(Wq, WqT, D_, D_, 0, 0);
    k_tcast<<<dim3(24, 24, 1), 256, 0, stream>>>(Wk, WkT, D_, D_, 0, 0);
    k_tcast<<<dim3(24, 24, 1), 256, 0, stream>>>(Wv, WvT, D_, D_, 0, 0);
    k_tcast<<<dim3(4, 24, 1), 256, 0, stream>>>(Wc, WcT, D_, R_, 0, 0);
    k_cast<<<(R_*D_+255)/256, 256, 0, stream>>>(rels, relsB, R_*D_);

    k_ent_emb<<<(N_*E_*D_+255)/256, 256, 0, stream>>>(seq, epos, entEmb);
    k_ent_att<<<(N_*E_*H_*C_+255)/256, 256, 0, stream>>>(att, epos, entAtt);
    k_gather_ht<<<(N_*P_*D_+255)/256, 256, 0, stream>>>(entEmb, hts, bcat);
    k_ht_att<<<NP, 256, 0, stream>>>(entAtt, hts, bhtAtt);

    // rs = batched bhtAtt(n) @ seqT(n)^T -> bcat[:, 2D:3D]
    k_mfma_bt<<<dim3(6, 5, N_), 256, 0, stream>>>(
        bhtAtt, seqT, nullptr, nullptr, bcat + 2*D_,
        P_, D_, D_, C_, C_, C_, 0, D3_, 1,
        (long)P_*C_, 0, (long)D_*C_, 0, 0, 0, (long)P_*D3_, 0, 0, 0);

    // htr = tanh(bcat @ WeT^T + be) -> f32 htr + bf16 bhtr
    k_mfma_bt<<<dim3(6, 18, 1), 256, 0, stream>>>(
        bcat, WeT, be, htr, bhtr,
        NP, D_, D_, D3_, D3_, D3_, D_, D_, 1,
        0, 0, 0, 0, 0, 0, 0, 0, 1, 0);

    // q = bhtr @ WqT^T + bq -> bf16 bqb
    k_mfma_bt<<<dim3(6, 18, 1), 256, 0, stream>>>(
        bhtr, WqT, bq, nullptr, bqb,
        NP, D_, D_, D_, D_, D_, 0, D_, 1,
        0, 0, 0, 0, 0, 0, 0, 0, 0, 0);

    // k = relsB @ WkT^T + bk -> bf16 bkb (97 x 768)
    k_mfma_bt<<<dim3(6, 1, 1), 256, 0, stream>>>(
        relsB, WkT, bk, nullptr, bkb,
        R_, D_, D_, D_, D_, D_, 0, D_, 1,
        0, 0, 0, 0, 0, 0, 0, 0, 0, 0);

    // vT = (rels @ Wv)^T + bv (per-row bias) -> bf16 vT (768 x 128, cols>=97 zero)
    k_mfma_bt<<<dim3(1, 6, 1), 256, 0, stream>>>(
        WvT, relsB, bv, nullptr, vT,
        D_, R_, 128, D_, D_, D_, 0, 128, 1,
        0, 0, 0, 0, 0, 0, 0, 0, 0, 1);

    // scores1[h] = q_h @ k_h^T  (M=2208, N=97, K=64, batch 12) -> f32 (ld 128)
    k_mfma_bt<<<dim3(1, 18, 12), 256, 0, stream>>>(
        bqb, bkb, nullptr, scores1, nullptr,
        NP, R_, R_, HD_, D_, D_, 128, 0, 12,
        0, HD_, 0, HD_, 0, (long)NP*128, 0, 0, 0, 0);

    // softmax1 -> bf16 P1 (ld 128, zero-pad)
    k_softmax1<<<(H_*NP)/4, 256, 0, stream>>>(scores1, P1);

    // o1 = P1 @ vT^T (M=2208, N=64, K=128, batch 12) -> bf16 o1b (np, h*64+e)
    k_mfma_bt<<<dim3(1, 18, 12), 256, 0, stream>>>(
        P1, vT, nullptr, nullptr, o1b,
        NP, HD_, HD_, 128, 128, 128, 0, D_, 12,
        0, (long)NP*128, 0, (long)HD_*128, 0, 0, 0, HD_, 0, 0);

    // o1T = per-(n,h) transpose of o1b slice -> (64 x 576, zero-pad)
    k_o1t<<<dim3(18, 2, N_*H_), 256, 0, stream>>>(o1b, o1T);

    // scores2 = o1 @ o1^T per (n,h) (M=N=552, Npad=576, K=64) -> bf16 s2
    k_mfma_bt<<<dim3(5, 5, N_*H_), 256, 0, stream>>>(
        o1b, o1b, nullptr, nullptr, s2,
        P_, P_, 576, HD_, D_, D_, 0, 576, H_,
        (long)P_*D_, HD_, (long)P_*D_, HD_,
        0, 0, (long)H_*P_*576, (long)P_*576, 0, 0);

    // softmax2 in-place on s2 (rows 552 valid, ld 576, zero-pad)
    k_softmax2<<<(N_*H_*P_)/4, 256, 0, stream>>>(s2);

    // o2 = P2 @ o1T^T per (n,h) (M=552, N=64, K=576) -> f32 o2 (np, h*64+e)
    k_mfma_bt<<<dim3(1, 5, N_*H_), 256, 0, stream>>>(
        s2, o1T, nullptr, o2, nullptr,
        P_, HD_, HD_, 576, 576, 576, D_, 0, H_,
        (long)H_*P_*576, (long)P_*576, (long)H_*HD_*576, (long)HD_*576,
        (long)P_*D_, HD_, 0, 0, 0, 0);

    // x = LN(htr + tanh(o2)) -> bf16
    k_ln<<<NP, 256, 0, stream>>>(htr, o2, ln_g, ln_b, bxb);

    // logits = bxb @ WcT^T + bc -> f32 out
    k_mfma_bt<<<dim3(1, 18, 1), 256, 0, stream>>>(
        bxb, WcT, bc, out, nullptr,
        NP, R_, R_, D_, D_, D_, R_, 0, 1,
        0, 0, 0, 0, 0, 0, 0, 0, 0, 0);
}

// Round 4
// 731.592 us; speedup vs baseline: 2.1540x; 1.0437x over previous
//
#include <hip/hip_runtime.h>
#include <hip/hip_bf16.h>

#define N_ 4
#define C_ 1024
#define D_ 768
#define H_ 12
#define E_ 24
#define M_ 4
#define P_ 552
#define R_ 97
#define HD_ 64
#define D3_ (3*D_)
#define NP_ (N_*P_)

#define SCALE_ 0.036084391824351615f  // 1/sqrt(768)

typedef __attribute__((ext_vector_type(8))) short v8s;
typedef __attribute__((ext_vector_type(4))) float v4f;

__device__ inline ushort f2bf(float x) {
    union { float f; unsigned u; } v; v.f = x;
    unsigned r = (v.u + 0x7FFF + ((v.u >> 16) & 1)) >> 16;
    return (ushort)r;
}

// ---------------- K1: ent_emb = logsumexp over M mentions ----------------
__global__ void k_ent_emb(const float* __restrict__ seq, const int* __restrict__ epos,
                          float* __restrict__ entEmb) {
    int idx = blockIdx.x * blockDim.x + threadIdx.x;   // over N*E*D
    if (idx >= N_*E_*D_) return;
    int d  = idx % D_;
    int ne = idx / D_;
    int e  = ne % E_;
    int n  = ne / E_;
    const int* pp = epos + (n*E_ + e)*M_;
    float v[M_];
    float mx = -1e30f;
    #pragma unroll
    for (int m = 0; m < M_; m++) {
        int pos = pp[m] + 1;  // OFFSET
        v[m] = seq[((long)n*C_ + pos)*D_ + d];
        mx = fmaxf(mx, v[m]);
    }
    float s = 0.f;
    #pragma unroll
    for (int m = 0; m < M_; m++) s += expf(v[m] - mx);
    entEmb[idx] = mx + logf(s);
}

// ---------------- K2: ent_att = mean over M of attention rows ----------------
__global__ void k_ent_att(const float* __restrict__ att, const int* __restrict__ epos,
                          float* __restrict__ entAtt) {
    long idx = (long)blockIdx.x * blockDim.x + threadIdx.x;  // over N*E*H*C
    if (idx >= (long)N_*E_*H_*C_) return;
    int c = idx % C_;
    long r = idx / C_;
    int h = r % H_; r /= H_;
    int e = r % E_;
    int n = r / E_;
    const int* pp = epos + (n*E_ + e)*M_;
    float s = 0.f;
    #pragma unroll
    for (int m = 0; m < M_; m++) {
        int pos = pp[m] + 1;
        s += att[(((long)n*H_ + h)*C_ + pos)*C_ + c];
    }
    entAtt[idx] = s * (1.0f / M_);
}

// ---------------- K3: gather hs/ts into bf16 concat buffer ----------------
__global__ void k_gather_ht(const float* __restrict__ entEmb, const int* __restrict__ hts,
                            ushort* __restrict__ bcat) {
    int idx = blockIdx.x * blockDim.x + threadIdx.x;  // over N*P*D
    if (idx >= N_*P_*D_) return;
    int d  = idx % D_;
    int np = idx / D_;
    int p  = np % P_;
    int n  = np / P_;
    int hi = hts[(n*P_ + p)*2 + 0];
    int ti = hts[(n*P_ + p)*2 + 1];
    bcat[(long)np*D3_ + d]       = f2bf(entEmb[((long)n*E_ + hi)*D_ + d]);
    bcat[(long)np*D3_ + D_ + d]  = f2bf(entEmb[((long)n*E_ + ti)*D_ + d]);
}

// ---------------- K4: ht_att (mean over H of h_att*t_att, normalized), bf16 out ----------------
__global__ void k_ht_att(const float* __restrict__ entAtt, const int* __restrict__ hts,
                         ushort* __restrict__ bhtAtt) {
    int np = blockIdx.x;           // N*P blocks
    int p = np % P_, n = np / P_;
    int t = threadIdx.x;           // 256 threads
    int hi = hts[(n*P_ + p)*2 + 0];
    int ti = hts[(n*P_ + p)*2 + 1];
    const float* ha = entAtt + ((long)n*E_ + hi)*H_*C_;
    const float* ta = entAtt + ((long)n*E_ + ti)*H_*C_;
    float vals[C_/256];
    float lsum = 0.f;
    #pragma unroll
    for (int i = 0; i < C_/256; i++) {
        int c = t + i*256;
        float s = 0.f;
        #pragma unroll
        for (int h = 0; h < H_; h++) s += ha[h*C_ + c] * ta[h*C_ + c];
        s *= (1.0f / H_);
        vals[i] = s;
        lsum += s;
    }
    __shared__ float red[256];
    red[t] = lsum; __syncthreads();
    for (int s1 = 128; s1; s1 >>= 1) { if (t < s1) red[t] += red[t+s1]; __syncthreads(); }
    float inv = 1.0f / (red[0] + 1e-5f);
    #pragma unroll
    for (int i = 0; i < C_/256; i++)
        bhtAtt[(long)np*C_ + t + i*256] = f2bf(vals[i] * inv);
}

// ---------------- transpose + cast: X (K x N, f32) -> Xt (N x K, bf16) ----------------
__global__ __launch_bounds__(256) void k_tcast(const float* __restrict__ X, ushort* __restrict__ Xt,
                                               int K, int N, long sX, long sXt) {
    X  += (long)blockIdx.z * sX;
    Xt += (long)blockIdx.z * sXt;
    __shared__ float tile[32][33];
    int t = threadIdx.x;
    int row = t >> 5, col = t & 31;
    int r0 = blockIdx.y * 32, c0 = blockIdx.x * 32;
    #pragma unroll
    for (int i = 0; i < 4; i++) {
        int r = r0 + row + i*8, c = c0 + col;
        tile[row + i*8][col] = (r < K && c < N) ? X[(long)r*N + c] : 0.f;
    }
    __syncthreads();
    #pragma unroll
    for (int i = 0; i < 4; i++) {
        int n = c0 + row + i*8, k = r0 + col;
        if (n < N && k < K) Xt[(long)n*K + k] = f2bf(tile[col][row + i*8]);
    }
}

// ---------------- merged transpose+cast for Wq/Wk/Wv (each 768x768) ----------------
__global__ __launch_bounds__(256) void k_tcast3(const float* __restrict__ A0,
                                                const float* __restrict__ A1,
                                                const float* __restrict__ A2,
                                                ushort* __restrict__ Y) {
    const float* X = (blockIdx.z == 0) ? A0 : (blockIdx.z == 1) ? A1 : A2;
    ushort* Xt = Y + (size_t)blockIdx.z * D_ * D_;
    __shared__ float tile[32][33];
    int t = threadIdx.x;
    int row = t >> 5, col = t & 31;
    int r0 = blockIdx.y * 32, c0 = blockIdx.x * 32;
    #pragma unroll
    for (int i = 0; i < 4; i++)
        tile[row + i*8][col] = X[(long)(r0 + row + i*8)*D_ + c0 + col];
    __syncthreads();
    #pragma unroll
    for (int i = 0; i < 4; i++)
        Xt[(long)(c0 + row + i*8)*D_ + r0 + col] = f2bf(tile[col][row + i*8]);
}

// ---------------- elementwise cast f32 -> bf16 ----------------
__global__ void k_cast(const float* __restrict__ x, ushort* __restrict__ y, int n) {
    int i = blockIdx.x * blockDim.x + threadIdx.x;
    if (i < n) y[i] = f2bf(x[i]);
}

// ---------------- generalized bf16 MFMA GEMM: C = act(A @ Bt^T + bias) ----------------
__global__ __launch_bounds__(256) void k_mfma_bt(
        const ushort* __restrict__ A, const ushort* __restrict__ Bt,
        const float* __restrict__ bias, float* __restrict__ Cf, ushort* __restrict__ Cb,
        int M, int N, int Npad, int K,
        int lda, int ldb, int ldcf, int ldcb, int nb2,
        long sA1, long sA2, long sB1, long sB2,
        long sCf1, long sCf2, long sCb1, long sCb2,
        int act, int biasM) {
    int z = blockIdx.z;
    int b1 = z / nb2, b2 = z % nb2;
    A  += b1*sA1 + b2*sA2;
    Bt += b1*sB1 + b2*sB2;
    long cfo = b1*sCf1 + b2*sCf2;
    long cbo = b1*sCb1 + b2*sCb2;
    __shared__ ushort As[128*32];
    __shared__ ushort Bs[128*32];
    int t = threadIdx.x;
    int m0 = blockIdx.y * 128, n0 = blockIdx.x * 128;
    int lr = t >> 2;            // 0..63
    int lc = (t & 3) * 8;       // 0,8,16,24
    int wv = t >> 6, lane = t & 63;
    int quad = lane >> 4, lm = lane & 15;
    int wm = (wv >> 1) * 64, wn = (wv & 1) * 64;

    v4f acc[4][4];
    #pragma unroll
    for (int i = 0; i < 4; i++)
        #pragma unroll
        for (int j = 0; j < 4; j++)
            acc[i][j] = (v4f){0.f, 0.f, 0.f, 0.f};

    const uint4 zero4 = {0u,0u,0u,0u};
    for (int k0 = 0; k0 < K; k0 += 32) {
        #pragma unroll
        for (int half = 0; half < 2; half++) {
            int row = lr + half*64;
            int gm = m0 + row;
            uint4 val = zero4;
            if (gm < M) val = *(const uint4*)(A + (long)gm*lda + k0 + lc);
            *(uint4*)(&As[row*32 + lc]) = val;
        }
        #pragma unroll
        for (int half = 0; half < 2; half++) {
            int row = lr + half*64;
            int gn = n0 + row;
            uint4 val = zero4;
            if (gn < N) val = *(const uint4*)(Bt + (long)gn*ldb + k0 + lc);
            *(uint4*)(&Bs[row*32 + lc]) = val;
        }
        __syncthreads();
        v8s a[4], b[4];
        #pragma unroll
        for (int i = 0; i < 4; i++)
            a[i] = *(const v8s*)(&As[(wm + i*16 + lm)*32 + quad*8]);
        #pragma unroll
        for (int j = 0; j < 4; j++)
            b[j] = *(const v8s*)(&Bs[(wn + j*16 + lm)*32 + quad*8]);
        #pragma unroll
        for (int i = 0; i < 4; i++)
            #pragma unroll
            for (int j = 0; j < 4; j++)
                acc[i][j] = __builtin_amdgcn_mfma_f32_16x16x32_bf16(a[i], b[j], acc[i][j], 0, 0, 0);
        __syncthreads();
    }

    #pragma unroll
    for (int j = 0; j < 4; j++) {
        int gn = n0 + wn + j*16 + lm;
        if (gn >= Npad) continue;
        bool vld = gn < N;
        float bvn = (bias && !biasM && vld) ? bias[gn] : 0.f;
        #pragma unroll
        for (int i = 0; i < 4; i++) {
            #pragma unroll
            for (int reg = 0; reg < 4; reg++) {
                int gm = m0 + wm + i*16 + quad*4 + reg;
                if (gm >= M) continue;
                float v = 0.f;
                if (vld) {
                    v = acc[i][j][reg] + bvn;
                    if (bias && biasM) v += bias[gm];
                    if (act == 1) v = tanhf(v);
                }
                if (Cf) Cf[cfo + (long)gm*ldcf + gn] = v;
                if (Cb) Cb[cbo + (long)gm*ldcb + gn] = f2bf(v);
            }
        }
    }
}

// ---------------- fused attn1: scores1 + softmax + P@V, per (m-tile, head) ----------------
// grid (18, 12), 256 threads. q: bqb (NP x 768, head slice). k: bkb (97 x 768).
// vT: (768 x 128) rows h*64+e, zero cols >= 97. Outputs o1b (np, h*64+e) and o1T (z, e, q ld576).
__global__ __launch_bounds__(256) void k_attn1f(
        const ushort* __restrict__ qb, const ushort* __restrict__ kb,
        const ushort* __restrict__ vT, ushort* __restrict__ o1b, ushort* __restrict__ o1T) {
    int mt = blockIdx.x, h = blockIdx.y;
    int m0 = mt * 128;
    __shared__ ushort U[128*128];      // Qs[128*64] | Ks[128*64]; later Ps[128*128]
    __shared__ ushort Vs[64*128];
    __shared__ float rowm[2][128];
    __shared__ float rowl[2][128];
    ushort* Qs = U;
    ushort* Ks = U + 128*64;
    ushort* Ps = U;
    int t = threadIdx.x;
    const uint4 z4 = {0u,0u,0u,0u};
    #pragma unroll
    for (int i = 0; i < 4; i++) {
        int id = t + i*256;            // 0..1023
        int row = id >> 3, c8 = (id & 7) * 8;
        int np = m0 + row;
        uint4 qv = z4;
        if (np < NP_) qv = *(const uint4*)(qb + (long)np*D_ + h*HD_ + c8);
        *(uint4*)(Qs + row*64 + c8) = qv;
        uint4 kv = z4;
        if (row < R_) kv = *(const uint4*)(kb + (long)row*D_ + h*HD_ + c8);
        *(uint4*)(Ks + row*64 + c8) = kv;
    }
    #pragma unroll
    for (int i = 0; i < 4; i++) {
        int id = t + i*256;
        int e = id >> 4, c8 = (id & 15) * 8;
        *(uint4*)(Vs + e*128 + c8) = *(const uint4*)(vT + ((long)h*HD_ + e)*128 + c8);
    }
    __syncthreads();
    int wv = t >> 6, lane = t & 63;
    int quad = lane >> 4, lm = lane & 15;
    int wm = (wv >> 1) * 64, wn = (wv & 1) * 64;
    int side = wv & 1;

    v4f acc[4][4];
    #pragma unroll
    for (int i = 0; i < 4; i++)
        #pragma unroll
        for (int j = 0; j < 4; j++)
            acc[i][j] = (v4f){0.f,0.f,0.f,0.f};
    #pragma unroll
    for (int k0 = 0; k0 < 64; k0 += 32) {
        v8s a[4], b[4];
        #pragma unroll
        for (int i = 0; i < 4; i++) a[i] = *(const v8s*)(Qs + (wm + i*16 + lm)*64 + k0 + quad*8);
        #pragma unroll
        for (int j = 0; j < 4; j++) b[j] = *(const v8s*)(Ks + (wn + j*16 + lm)*64 + k0 + quad*8);
        #pragma unroll
        for (int i = 0; i < 4; i++)
            #pragma unroll
            for (int j = 0; j < 4; j++)
                acc[i][j] = __builtin_amdgcn_mfma_f32_16x16x32_bf16(a[i], b[j], acc[i][j], 0, 0, 0);
    }
    // scale + mask cols >= 97
    #pragma unroll
    for (int j = 0; j < 4; j++) {
        int col = wn + j*16 + lm;
        bool ok = col < R_;
        #pragma unroll
        for (int i = 0; i < 4; i++)
            #pragma unroll
            for (int reg = 0; reg < 4; reg++)
                acc[i][j][reg] = ok ? acc[i][j][reg]*SCALE_ : -1e30f;
    }
    // per-row max (this wave's 64-col side)
    #pragma unroll
    for (int i = 0; i < 4; i++)
        #pragma unroll
        for (int reg = 0; reg < 4; reg++) {
            float m = fmaxf(fmaxf(acc[i][0][reg], acc[i][1][reg]),
                            fmaxf(acc[i][2][reg], acc[i][3][reg]));
            #pragma unroll
            for (int o = 1; o < 16; o <<= 1) m = fmaxf(m, __shfl_xor(m, o));
            if (lm == 0) rowm[side][wm + i*16 + quad*4 + reg] = m;
        }
    __syncthreads();
    // exp + per-row partial sums
    #pragma unroll
    for (int i = 0; i < 4; i++)
        #pragma unroll
        for (int reg = 0; reg < 4; reg++) {
            int r = wm + i*16 + quad*4 + reg;
            float m = fmaxf(rowm[0][r], rowm[1][r]);
            float s = 0.f;
            #pragma unroll
            for (int j = 0; j < 4; j++) {
                float e = expf(acc[i][j][reg] - m);
                acc[i][j][reg] = e;
                s += e;
            }
            #pragma unroll
            for (int o = 1; o < 16; o <<= 1) s += __shfl_xor(s, o);
            if (lm == 0) rowl[side][r] = s;
        }
    __syncthreads();
    // write P (normalized, bf16) into Ps (aliases Qs/Ks — all waves past MFMA)
    #pragma unroll
    for (int i = 0; i < 4; i++)
        #pragma unroll
        for (int reg = 0; reg < 4; reg++) {
            int r = wm + i*16 + quad*4 + reg;
            float inv = 1.0f / (rowl[0][r] + rowl[1][r]);
            #pragma unroll
            for (int j = 0; j < 4; j++)
                Ps[r*128 + wn + j*16 + lm] = f2bf(acc[i][j][reg] * inv);
        }
    __syncthreads();
    // o1 = P @ V: band layout, each wave 32 rows x 64 cols, K=128
    v4f acc2[2][4];
    #pragma unroll
    for (int i = 0; i < 2; i++)
        #pragma unroll
        for (int j = 0; j < 4; j++)
            acc2[i][j] = (v4f){0.f,0.f,0.f,0.f};
    int wm2 = wv * 32;
    #pragma unroll
    for (int k0 = 0; k0 < 128; k0 += 32) {
        v8s a2[2], b2[4];
        #pragma unroll
        for (int i = 0; i < 2; i++) a2[i] = *(const v8s*)(Ps + (wm2 + i*16 + lm)*128 + k0 + quad*8);
        #pragma unroll
        for (int j = 0; j < 4; j++) b2[j] = *(const v8s*)(Vs + (j*16 + lm)*128 + k0 + quad*8);
        #pragma unroll
        for (int i = 0; i < 2; i++)
            #pragma unroll
            for (int j = 0; j < 4; j++)
                acc2[i][j] = __builtin_amdgcn_mfma_f32_16x16x32_bf16(a2[i], b2[j], acc2[i][j], 0, 0, 0);
    }
    #pragma unroll
    for (int i = 0; i < 2; i++)
        #pragma unroll
        for (int j = 0; j < 4; j++)
            #pragma unroll
            for (int reg = 0; reg < 4; reg++) {
                int row = m0 + wm2 + i*16 + quad*4 + reg;
                if (row >= NP_) continue;
                int e = j*16 + lm;
                ushort bvv = f2bf(acc2[i][j][reg]);
                o1b[(long)row*D_ + h*HD_ + e] = bvv;
                int n = row / P_;
                int q = row - n*P_;
                o1T[(((long)(n*H_ + h))*HD_ + e)*576 + q] = bvv;
            }
}

// ---------------- fused attn2 (flash-style): scores2 + online softmax + P@V ----------------
// grid (5, 48): x = q-tile (128 rows of 552), y = n*H+h. 256 threads.
__global__ __launch_bounds__(256) void k_attn2f(
        const ushort* __restrict__ o1b, const ushort* __restrict__ o1T, float* __restrict__ o2) {
    int qt = blockIdx.x;
    int zz = blockIdx.y;
    int n = zz / H_, h = zz % H_;
    int q0 = qt * 128;
    __shared__ ushort Qs[128*64];
    __shared__ ushort KV[128*64];   // K-chunk, then V-chunk (same 16 KB)
    __shared__ ushort Ps[128*128];
    __shared__ float rowm[2][128], rowl[2][128];
    __shared__ float mrun[128], lrun[128], alphaS[128];
    int t = threadIdx.x;
    const ushort* base = o1b + (long)n*P_*D_ + h*HD_;
    const uint4 z4 = {0u,0u,0u,0u};
    #pragma unroll
    for (int i = 0; i < 4; i++) {
        int id = t + i*256;
        int row = id >> 3, c8 = (id & 7) * 8;
        int q = q0 + row;
        uint4 v = z4;
        if (q < P_) v = *(const uint4*)(base + (long)q*D_ + c8);
        *(uint4*)(Qs + row*64 + c8) = v;
    }
    if (t < 128) { mrun[t] = -1e30f; lrun[t] = 0.f; }
    __syncthreads();
    int wv = t >> 6, lane = t & 63;
    int quad = lane >> 4, lm = lane & 15;
    int wm = (wv >> 1) * 64, wn = (wv & 1) * 64;
    int side = wv & 1;
    int wm2 = wv * 32;
    v4f acc2[2][4];
    #pragma unroll
    for (int i = 0; i < 2; i++)
        #pragma unroll
        for (int j = 0; j < 4; j++)
            acc2[i][j] = (v4f){0.f,0.f,0.f,0.f};

    for (int c = 0; c < 5; c++) {
        // stage K-chunk
        #pragma unroll
        for (int i = 0; i < 4; i++) {
            int id = t + i*256;
            int row = id >> 3, c8 = (id & 7) * 8;
            int q = c*128 + row;
            uint4 v = z4;
            if (q < P_) v = *(const uint4*)(base + (long)q*D_ + c8);
            *(uint4*)(KV + row*64 + c8) = v;
        }
        __syncthreads();
        v4f acc[4][4];
        #pragma unroll
        for (int i = 0; i < 4; i++)
            #pragma unroll
            for (int j = 0; j < 4; j++)
                acc[i][j] = (v4f){0.f,0.f,0.f,0.f};
        #pragma unroll
        for (int k0 = 0; k0 < 64; k0 += 32) {
            v8s a[4], b[4];
            #pragma unroll
            for (int i = 0; i < 4; i++) a[i] = *(const v8s*)(Qs + (wm + i*16 + lm)*64 + k0 + quad*8);
            #pragma unroll
            for (int j = 0; j < 4; j++) b[j] = *(const v8s*)(KV + (wn + j*16 + lm)*64 + k0 + quad*8);
            #pragma unroll
            for (int i = 0; i < 4; i++)
                #pragma unroll
                for (int j = 0; j < 4; j++)
                    acc[i][j] = __builtin_amdgcn_mfma_f32_16x16x32_bf16(a[i], b[j], acc[i][j], 0, 0, 0);
        }
        // scale + mask
        #pragma unroll
        for (int j = 0; j < 4; j++) {
            int col = c*128 + wn + j*16 + lm;
            bool ok = col < P_;
            #pragma unroll
            for (int i = 0; i < 4; i++)
                #pragma unroll
                for (int reg = 0; reg < 4; reg++)
                    acc[i][j][reg] = ok ? acc[i][j][reg]*SCALE_ : -1e30f;
        }
        // chunk row max (per side)
        #pragma unroll
        for (int i = 0; i < 4; i++)
            #pragma unroll
            for (int reg = 0; reg < 4; reg++) {
                float m = fmaxf(fmaxf(acc[i][0][reg], acc[i][1][reg]),
                                fmaxf(acc[i][2][reg], acc[i][3][reg]));
                #pragma unroll
                for (int o = 1; o < 16; o <<= 1) m = fmaxf(m, __shfl_xor(m, o));
                if (lm == 0) rowm[side][wm + i*16 + quad*4 + reg] = m;
            }
        __syncthreads();
        // exp with running max; partial sums
        #pragma unroll
        for (int i = 0; i < 4; i++)
            #pragma unroll
            for (int reg = 0; reg < 4; reg++) {
                int r = wm + i*16 + quad*4 + reg;
                float mc = fmaxf(rowm[0][r], rowm[1][r]);
                float mn = fmaxf(mrun[r], mc);
                float s = 0.f;
                #pragma unroll
                for (int j = 0; j < 4; j++) {
                    float e = expf(acc[i][j][reg] - mn);
                    acc[i][j][reg] = e;
                    s += e;
                }
                #pragma unroll
                for (int o = 1; o < 16; o <<= 1) s += __shfl_xor(s, o);
                if (lm == 0) rowl[side][r] = s;
            }
        __syncthreads();
        // state update (one lane per row): alpha, l, m
        if (side == 0 && lm == 0) {
            #pragma unroll
            for (int i = 0; i < 4; i++)
                #pragma unroll
                for (int reg = 0; reg < 4; reg++) {
                    int r = wm + i*16 + quad*4 + reg;
                    float mo = mrun[r];
                    float mc = fmaxf(rowm[0][r], rowm[1][r]);
                    float mn = fmaxf(mo, mc);
                    float al = expf(mo - mn);
                    lrun[r] = lrun[r]*al + rowl[0][r] + rowl[1][r];
                    mrun[r] = mn;
                    alphaS[r] = al;
                }
        }
        // stage V-chunk into KV (K dead; all waves past MFMA due to rowm barrier)
        #pragma unroll
        for (int i = 0; i < 4; i++) {
            int id = t + i*256;
            int e = id >> 4, c8 = (id & 15) * 8;
            uint4 v = z4;
            if (c*128 + c8 < P_) v = *(const uint4*)(o1T + ((long)zz*HD_ + e)*576 + c*128 + c8);
            *(uint4*)(KV + e*128 + c8) = v;
        }
        // write P (unnormalized) bf16
        #pragma unroll
        for (int i = 0; i < 4; i++)
            #pragma unroll
            for (int reg = 0; reg < 4; reg++) {
                int r = wm + i*16 + quad*4 + reg;
                #pragma unroll
                for (int j = 0; j < 4; j++)
                    Ps[r*128 + wn + j*16 + lm] = f2bf(acc[i][j][reg]);
            }
        __syncthreads();
        // rescale O-acc, then accumulate P@V
        #pragma unroll
        for (int i = 0; i < 2; i++) {
            #pragma unroll
            for (int reg = 0; reg < 4; reg++) {
                float al = alphaS[wm2 + i*16 + quad*4 + reg];
                #pragma unroll
                for (int j = 0; j < 4; j++)
                    acc2[i][j][reg] *= al;
            }
        }
        #pragma unroll
        for (int k0 = 0; k0 < 128; k0 += 32) {
            v8s a2[2], b2[4];
            #pragma unroll
            for (int i = 0; i < 2; i++) a2[i] = *(const v8s*)(Ps + (wm2 + i*16 + lm)*128 + k0 + quad*8);
            #pragma unroll
            for (int j = 0; j < 4; j++) b2[j] = *(const v8s*)(KV + (j*16 + lm)*128 + k0 + quad*8);
            #pragma unroll
            for (int i = 0; i < 2; i++)
                #pragma unroll
                for (int j = 0; j < 4; j++)
                    acc2[i][j] = __builtin_amdgcn_mfma_f32_16x16x32_bf16(a2[i], b2[j], acc2[i][j], 0, 0, 0);
        }
        __syncthreads();   // protect KV/Ps before next chunk
    }
    // final normalize + write o2 f32
    #pragma unroll
    for (int i = 0; i < 2; i++)
        #pragma unroll
        for (int j = 0; j < 4; j++)
            #pragma unroll
            for (int reg = 0; reg < 4; reg++) {
                int row = wm2 + i*16 + quad*4 + reg;
                int q = q0 + row;
                if (q >= P_) continue;
                float l = lrun[row];
                o2[((long)n*P_ + q)*D_ + h*HD_ + j*16 + lm] = acc2[i][j][reg] / l;
            }
}

// ---------------- x = LN(htr + tanh(o2)) -> bf16 ----------------
__global__ void k_ln(const float* __restrict__ htr, const float* __restrict__ o2,
                     const float* __restrict__ g, const float* __restrict__ b,
                     ushort* __restrict__ bx) {
    int np = blockIdx.x;    // N*P blocks
    int t = threadIdx.x;    // 256 threads
    __shared__ float red[256];
    float v[D_/256];
    float s = 0.f;
    #pragma unroll
    for (int i = 0; i < D_/256; i++) {
        int d = t + i*256;
        float val = htr[(long)np*D_ + d] + tanhf(o2[(long)np*D_ + d]);
        v[i] = val; s += val;
    }
    red[t] = s; __syncthreads();
    for (int s1 = 128; s1; s1 >>= 1) { if (t < s1) red[t] += red[t+s1]; __syncthreads(); }
    float mu = red[0] * (1.0f/D_);
    __syncthreads();
    float s2 = 0.f;
    #pragma unroll
    for (int i = 0; i < D_/256; i++) { float dx = v[i]-mu; s2 += dx*dx; }
    red[t] = s2; __syncthreads();
    for (int s1 = 128; s1; s1 >>= 1) { if (t < s1) red[t] += red[t+s1]; __syncthreads(); }
    float inv = rsqrtf(red[0]*(1.0f/D_) + 1e-5f);
    #pragma unroll
    for (int i = 0; i < D_/256; i++) {
        int d = t + i*256;
        bx[(long)np*D_ + d] = f2bf((v[i]-mu)*inv*g[d] + b[d]);
    }
}

extern "C" void kernel_launch(void* const* d_in, const int* in_sizes, int n_in,
                              void* d_out, int out_size, void* d_ws, size_t ws_size,
                              hipStream_t stream) {
    const float* seq   = (const float*)d_in[0];
    const float* att   = (const float*)d_in[1];
    const int*   epos  = (const int*)d_in[2];
    const int*   hts   = (const int*)d_in[3];
    const float* rels  = (const float*)d_in[4];
    const float* We    = (const float*)d_in[5];
    const float* be    = (const float*)d_in[6];
    const float* Wq    = (const float*)d_in[7];
    const float* bq    = (const float*)d_in[8];
    const float* Wk    = (const float*)d_in[9];
    const float* bk    = (const float*)d_in[10];
    const float* Wv    = (const float*)d_in[11];
    const float* bv    = (const float*)d_in[12];
    const float* ln_g  = (const float*)d_in[13];
    const float* ln_b  = (const float*)d_in[14];
    const float* Wc    = (const float*)d_in[15];
    const float* bc    = (const float*)d_in[16];
    float* out = (float*)d_out;
    float* w = (float*)d_ws;

    const int NP = NP_;  // 2208

    // ---- f32 workspace ----
    float* entEmb  = w;                                 //    73,728
    float* entAtt  = entEmb  + (size_t)N_*E_*D_;        // 1,179,648
    float* htr     = entAtt  + (size_t)N_*E_*H_*C_;     // 1,695,744
    float* o2      = htr     + (size_t)NP*D_;           // 1,695,744
    // ---- bf16 workspace ----
    ushort* bhtAtt = (ushort*)(o2 + (size_t)NP*D_);     // 2,260,992
    ushort* bcat   = bhtAtt + (size_t)NP*C_;            // 5,087,232
    ushort* seqT   = bcat  + (size_t)NP*D3_;            // 3,145,728
    ushort* WeT    = seqT  + (size_t)N_*D_*C_;          // 1,769,472
    ushort* WqT    = WeT   + (size_t)D_*D3_;            //   589,824
    ushort* WkT    = WqT   + (size_t)D_*D_;             //   589,824
    ushort* WvT    = WkT   + (size_t)D_*D_;             //   589,824
    ushort* WcT    = WvT   + (size_t)D_*D_;             //    74,496
    ushort* relsB  = WcT   + (size_t)D_*R_;             //    74,496
    ushort* bhtr   = relsB + (size_t)R_*D_;             // 1,695,744
    ushort* bqb    = bhtr  + (size_t)NP*D_;             // 1,695,744
    ushort* bkb    = bqb   + (size_t)NP*D_;             //    74,496
    ushort* vT     = bkb   + (size_t)R_*D_;             //    98,304 (768 x 128)
    ushort* o1b    = vT    + (size_t)D_*128;            // 1,695,744
    ushort* o1T    = o1b   + (size_t)NP*D_;             // 1,769,472 (48 x 64 x 576)
    ushort* bxb    = o1T   + (size_t)48*HD_*576;        // 1,695,744

    // ---- operand transposes / casts ----
    k_tcast<<<dim3(24, 32, N_), 256, 0, stream>>>(seq, seqT, C_, D_, (long)C_*D_, (long)D_*C_);
    k_tcast<<<dim3(24, 72, 1), 256, 0, stream>>>(We, WeT, D3_, D_, 0, 0);
    k_tcast3<<<dim3(24, 24, 3), 256, 0, stream>>>(Wq, Wk, Wv, WqT);
    k_tcast<<<dim3(4, 24, 1), 256, 0, stream>>>(Wc, WcT, D_, R_, 0, 0);
    k_cast<<<(R_*D_+255)/256, 256, 0, stream>>>(rels, relsB, R_*D_);

    k_ent_emb<<<(N_*E_*D_+255)/256, 256, 0, stream>>>(seq, epos, entEmb);
    k_ent_att<<<(N_*E_*H_*C_+255)/256, 256, 0, stream>>>(att, epos, entAtt);
    k_gather_ht<<<(N_*P_*D_+255)/256, 256, 0, stream>>>(entEmb, hts, bcat);
    k_ht_att<<<NP, 256, 0, stream>>>(entAtt, hts, bhtAtt);

    // rs = batched bhtAtt(n) @ seqT(n)^T -> bcat[:, 2D:3D]
    k_mfma_bt<<<dim3(6, 5, N_), 256, 0, stream>>>(
        bhtAtt, seqT, nullptr, nullptr, bcat + 2*D_,
        P_, D_, D_, C_, C_, C_, 0, D3_, 1,
        (long)P_*C_, 0, (long)D_*C_, 0, 0, 0, (long)P_*D3_, 0, 0, 0);

    // htr = tanh(bcat @ WeT^T + be) -> f32 htr + bf16 bhtr
    k_mfma_bt<<<dim3(6, 18, 1), 256, 0, stream>>>(
        bcat, WeT, be, htr, bhtr,
        NP, D_, D_, D3_, D3_, D3_, D_, D_, 1,
        0, 0, 0, 0, 0, 0, 0, 0, 1, 0);

    // q = bhtr @ WqT^T + bq -> bf16 bqb
    k_mfma_bt<<<dim3(6, 18, 1), 256, 0, stream>>>(
        bhtr, WqT, bq, nullptr, bqb,
        NP, D_, D_, D_, D_, D_, 0, D_, 1,
        0, 0, 0, 0, 0, 0, 0, 0, 0, 0);

    // k = relsB @ WkT^T + bk -> bf16 bkb (97 x 768)
    k_mfma_bt<<<dim3(6, 1, 1), 256, 0, stream>>>(
        relsB, WkT, bk, nullptr, bkb,
        R_, D_, D_, D_, D_, D_, 0, D_, 1,
        0, 0, 0, 0, 0, 0, 0, 0, 0, 0);

    // vT = (rels @ Wv)^T + bv (per-row bias) -> bf16 vT (768 x 128, cols>=97 zero)
    k_mfma_bt<<<dim3(1, 6, 1), 256, 0, stream>>>(
        WvT, relsB, bv, nullptr, vT,
        D_, R_, 128, D_, D_, D_, 0, 128, 1,
        0, 0, 0, 0, 0, 0, 0, 0, 0, 1);

    // fused attn1: scores1+softmax+P@V -> o1b + o1T
    k_attn1f<<<dim3(18, 12), 256, 0, stream>>>(bqb, bkb, vT, o1b, o1T);

    // fused attn2 (flash): -> o2 f32
    k_attn2f<<<dim3(5, 48), 256, 0, stream>>>(o1b, o1T, o2);

    // x = LN(htr + tanh(o2)) -> bf16
    k_ln<<<NP, 256, 0, stream>>>(htr, o2, ln_g, ln_b, bxb);

    // logits = bxb @ WcT^T + bc -> f32 out
    k_mfma_bt<<<dim3(1, 18, 1), 256, 0, stream>>>(
        bxb, WcT, bc, out, nullptr,
        NP, R_, R_, D_, D_, D_, R_, 0, 1,
        0, 0, 0, 0, 0, 0, 0, 0, 0, 0);
}

// Round 5
// 615.063 us; speedup vs baseline: 2.5621x; 1.1895x over previous
//
#include <hip/hip_runtime.h>
#include <hip/hip_bf16.h>

#define N_ 4
#define C_ 1024
#define D_ 768
#define H_ 12
#define E_ 24
#define M_ 4
#define P_ 552
#define R_ 97
#define HD_ 64
#define D3_ (3*D_)
#define NP_ (N_*P_)

#define SCALE_ 0.036084391824351615f  // 1/sqrt(768)

typedef __attribute__((ext_vector_type(8))) short v8s;
typedef __attribute__((ext_vector_type(4))) float v4f;

__device__ inline ushort f2bf(float x) {
    union { float f; unsigned u; } v; v.f = x;
    unsigned r = (v.u + 0x7FFF + ((v.u >> 16) & 1)) >> 16;
    return (ushort)r;
}

// async global->LDS 16B (direct-to-shared DMA, counts on vmcnt)
__device__ inline void gl_lds16(const ushort* g, ushort* l) {
    __builtin_amdgcn_global_load_lds(
        (const __attribute__((address_space(1))) unsigned int*)(const void*)g,
        (__attribute__((address_space(3))) unsigned int*)(void*)l,
        16, 0, 0);
}

// ---------------- merged prep: all weight transposes + rels cast ----------------
__device__ inline void tcast32(const float* __restrict__ X, ushort* __restrict__ Xt,
                               int K, int N, int yt, int xt, float (*tile)[33], int t) {
    int row = t >> 5, col = t & 31;
    int r0 = yt * 32, c0 = xt * 32;
    #pragma unroll
    for (int i = 0; i < 4; i++) {
        int r = r0 + row + i*8, c = c0 + col;
        tile[row + i*8][col] = (r < K && c < N) ? X[(long)r*N + c] : 0.f;
    }
    __syncthreads();
    #pragma unroll
    for (int i = 0; i < 4; i++) {
        int n = c0 + row + i*8, k = r0 + col;
        if (n < N && k < K) Xt[(long)n*K + k] = f2bf(tile[col][row + i*8]);
    }
}

__global__ __launch_bounds__(256) void k_prep(
        const float* __restrict__ seq, const float* __restrict__ We,
        const float* __restrict__ Wq, const float* __restrict__ Wk,
        const float* __restrict__ Wv, const float* __restrict__ Wc,
        const float* __restrict__ rels,
        ushort* __restrict__ seqT, ushort* __restrict__ WeT, ushort* __restrict__ W3T,
        ushort* __restrict__ WcT, ushort* __restrict__ relsB) {
    __shared__ float tile[32][33];
    int b = blockIdx.x, t = threadIdx.x;
    if (b < 3072) {                    // seqT: 4 batches x (24 x 32) tiles
        int z = b / 768, r = b % 768;
        tcast32(seq + (long)z*C_*D_, seqT + (long)z*D_*C_, C_, D_, r/24, r%24, tile, t);
    } else if (b < 4800) {             // WeT: 24 x 72
        int r = b - 3072;
        tcast32(We, WeT, D3_, D_, r/24, r%24, tile, t);
    } else if (b < 6528) {             // Wq/Wk/Wv: 3 x (24 x 24)
        int r3 = b - 4800;
        int z = r3 / 576, r = r3 % 576;
        const float* X = (z == 0) ? Wq : (z == 1) ? Wk : Wv;
        tcast32(X, W3T + (size_t)z*D_*D_, D_, D_, r/24, r%24, tile, t);
    } else if (b < 6624) {             // WcT: 4 x 24
        int r = b - 6528;
        tcast32(Wc, WcT, D_, R_, r/4, r%4, tile, t);
    } else {                           // rels cast: 73 blocks x 1024 elems
        int base = (b - 6624) * 1024 + t * 4;
        #pragma unroll
        for (int j = 0; j < 4; j++) {
            int i = base + j;
            if (i < R_*D_) relsB[i] = f2bf(rels[i]);
        }
    }
}

// ---------------- merged: ent_emb (logsumexp) + ent_att (mean) ----------------
__global__ void k_ent(const float* __restrict__ seq, const float* __restrict__ att,
                      const int* __restrict__ epos,
                      float* __restrict__ entEmb, float* __restrict__ entAtt) {
    int b = blockIdx.x, t = threadIdx.x;
    if (b < 288) {                     // ent_emb over N*E*D = 288*256 exactly
        int idx = b*256 + t;
        int d  = idx % D_;
        int ne = idx / D_;
        int e  = ne % E_;
        int n  = ne / E_;
        const int* pp = epos + (n*E_ + e)*M_;
        float v[M_];
        float mx = -1e30f;
        #pragma unroll
        for (int m = 0; m < M_; m++) {
            int pos = pp[m] + 1;  // OFFSET
            v[m] = seq[((long)n*C_ + pos)*D_ + d];
            mx = fmaxf(mx, v[m]);
        }
        float s = 0.f;
        #pragma unroll
        for (int m = 0; m < M_; m++) s += expf(v[m] - mx);
        entEmb[idx] = mx + logf(s);
    } else {                           // ent_att over N*E*H*C = 4608*256 exactly
        long idx = (long)(b - 288)*256 + t;
        int c = idx % C_;
        long r = idx / C_;
        int h = r % H_; r /= H_;
        int e = r % E_;
        int n = r / E_;
        const int* pp = epos + (n*E_ + e)*M_;
        float s = 0.f;
        #pragma unroll
        for (int m = 0; m < M_; m++) {
            int pos = pp[m] + 1;
            s += att[(((long)n*H_ + h)*C_ + pos)*C_ + c];
        }
        entAtt[idx] = s * (1.0f / M_);
    }
}

// ---------------- merged: gather hs/ts + ht_att ----------------
__global__ void k_gath(const float* __restrict__ entEmb, const float* __restrict__ entAtt,
                       const int* __restrict__ hts,
                       ushort* __restrict__ bcat, ushort* __restrict__ bhtAtt) {
    __shared__ float red[256];
    int b = blockIdx.x, t = threadIdx.x;
    if (b < 6624) {                    // gather over N*P*D = 6624*256 exactly
        int idx = b*256 + t;
        int d  = idx % D_;
        int np = idx / D_;
        int p  = np % P_;
        int n  = np / P_;
        int hi = hts[(n*P_ + p)*2 + 0];
        int ti = hts[(n*P_ + p)*2 + 1];
        bcat[(long)np*D3_ + d]       = f2bf(entEmb[((long)n*E_ + hi)*D_ + d]);
        bcat[(long)np*D3_ + D_ + d]  = f2bf(entEmb[((long)n*E_ + ti)*D_ + d]);
    } else {                           // ht_att: 2208 blocks
        int np = b - 6624;
        int p = np % P_, n = np / P_;
        int hi = hts[(n*P_ + p)*2 + 0];
        int ti = hts[(n*P_ + p)*2 + 1];
        const float* ha = entAtt + ((long)n*E_ + hi)*H_*C_;
        const float* ta = entAtt + ((long)n*E_ + ti)*H_*C_;
        float vals[C_/256];
        float lsum = 0.f;
        #pragma unroll
        for (int i = 0; i < C_/256; i++) {
            int c = t + i*256;
            float s = 0.f;
            #pragma unroll
            for (int h = 0; h < H_; h++) s += ha[h*C_ + c] * ta[h*C_ + c];
            s *= (1.0f / H_);
            vals[i] = s;
            lsum += s;
        }
        red[t] = lsum; __syncthreads();
        for (int s1 = 128; s1; s1 >>= 1) { if (t < s1) red[t] += red[t+s1]; __syncthreads(); }
        float inv = 1.0f / (red[0] + 1e-5f);
        #pragma unroll
        for (int i = 0; i < C_/256; i++)
            bhtAtt[(long)np*C_ + t + i*256] = f2bf(vals[i] * inv);
    }
}

// ---------------- bf16 MFMA GEMM, double-buffered LDS + global_load_lds staging ----------------
// A: M x K bf16 (lda). Bt: N x K bf16 (ldb). K % 32 == 0. OOB rows clamped (masked in epilogue).
__global__ __launch_bounds__(256) void k_mfma_bt(
        const ushort* __restrict__ A, const ushort* __restrict__ Bt,
        const float* __restrict__ bias, float* __restrict__ Cf, ushort* __restrict__ Cb,
        int M, int N, int Npad, int K,
        int lda, int ldb, int ldcf, int ldcb, int nb2,
        long sA1, long sA2, long sB1, long sB2,
        long sCf1, long sCf2, long sCb1, long sCb2,
        int act, int biasM) {
    int z = blockIdx.z;
    int b1 = z / nb2, b2 = z % nb2;
    A  += b1*sA1 + b2*sA2;
    Bt += b1*sB1 + b2*sB2;
    long cfo = b1*sCf1 + b2*sCf2;
    long cbo = b1*sCb1 + b2*sCb2;
    __shared__ ushort As[2][128*32];
    __shared__ ushort Bs[2][128*32];
    int t = threadIdx.x;
    int m0 = blockIdx.y * 128, n0 = blockIdx.x * 128;
    int lr = t >> 2;            // 0..63
    int lc = (t & 3) * 8;       // 0,8,16,24
    int wv = t >> 6, lane = t & 63;
    int quad = lane >> 4, lm = lane & 15;
    int wm = (wv >> 1) * 64, wn = (wv & 1) * 64;

    // clamped staging addresses (OOB rows re-read a valid row; masked at epilogue)
    const ushort* pA0 = A + (long)min(m0 + lr,      M-1)*lda + lc;
    const ushort* pA1 = A + (long)min(m0 + lr + 64, M-1)*lda + lc;
    const ushort* pB0 = Bt + (long)min(n0 + lr,      N-1)*ldb + lc;
    const ushort* pB1 = Bt + (long)min(n0 + lr + 64, N-1)*ldb + lc;

    v4f acc[4][4];
    #pragma unroll
    for (int i = 0; i < 4; i++)
        #pragma unroll
        for (int j = 0; j < 4; j++)
            acc[i][j] = (v4f){0.f, 0.f, 0.f, 0.f};

    // prologue: stage tile 0 into buf 0
    gl_lds16(pA0, &As[0][t*8]);
    gl_lds16(pA1, &As[0][2048 + t*8]);
    gl_lds16(pB0, &Bs[0][t*8]);
    gl_lds16(pB1, &Bs[0][2048 + t*8]);

    int cur = 0;
    for (int k0 = 0; k0 < K; k0 += 32) {
        __syncthreads();   // drains async loads for buf `cur` + protects prev MFMA reads
        if (k0 + 32 < K) {
            int nb = cur ^ 1;
            gl_lds16(pA0 + k0 + 32, &As[nb][t*8]);
            gl_lds16(pA1 + k0 + 32, &As[nb][2048 + t*8]);
            gl_lds16(pB0 + k0 + 32, &Bs[nb][t*8]);
            gl_lds16(pB1 + k0 + 32, &Bs[nb][2048 + t*8]);
        }
        v8s a[4], b[4];
        #pragma unroll
        for (int i = 0; i < 4; i++)
            a[i] = *(const v8s*)(&As[cur][(wm + i*16 + lm)*32 + quad*8]);
        #pragma unroll
        for (int j = 0; j < 4; j++)
            b[j] = *(const v8s*)(&Bs[cur][(wn + j*16 + lm)*32 + quad*8]);
        #pragma unroll
        for (int i = 0; i < 4; i++)
            #pragma unroll
            for (int j = 0; j < 4; j++)
                acc[i][j] = __builtin_amdgcn_mfma_f32_16x16x32_bf16(a[i], b[j], acc[i][j], 0, 0, 0);
        cur ^= 1;
    }

    // epilogue: C/D layout col=lane&15, row=quad*4+reg
    #pragma unroll
    for (int j = 0; j < 4; j++) {
        int gn = n0 + wn + j*16 + lm;
        if (gn >= Npad) continue;
        bool vld = gn < N;
        float bvn = (bias && !biasM && vld) ? bias[gn] : 0.f;
        #pragma unroll
        for (int i = 0; i < 4; i++) {
            #pragma unroll
            for (int reg = 0; reg < 4; reg++) {
                int gm = m0 + wm + i*16 + quad*4 + reg;
                if (gm >= M) continue;
                float v = 0.f;
                if (vld) {
                    v = acc[i][j][reg] + bvn;
                    if (bias && biasM) v += bias[gm];
                    if (act == 1) v = tanhf(v);
                }
                if (Cf) Cf[cfo + (long)gm*ldcf + gn] = v;
                if (Cb) Cb[cbo + (long)gm*ldcb + gn] = f2bf(v);
            }
        }
    }
}

// ---------------- fused attn1: scores1 + softmax + P@V, per (m-tile, head) ----------------
__global__ __launch_bounds__(256) void k_attn1f(
        const ushort* __restrict__ qb, const ushort* __restrict__ kb,
        const ushort* __restrict__ vT, ushort* __restrict__ o1b, ushort* __restrict__ o1T) {
    int mt = blockIdx.x, h = blockIdx.y;
    int m0 = mt * 128;
    __shared__ ushort U[128*128];      // Qs[128*64] | Ks[128*64]; later Ps[128*128]
    __shared__ ushort Vs[64*128];
    __shared__ float rowm[2][128];
    __shared__ float rowl[2][128];
    ushort* Qs = U;
    ushort* Ks = U + 128*64;
    ushort* Ps = U;
    int t = threadIdx.x;
    const uint4 z4 = {0u,0u,0u,0u};
    #pragma unroll
    for (int i = 0; i < 4; i++) {
        int id = t + i*256;            // 0..1023
        int row = id >> 3, c8 = (id & 7) * 8;
        int np = m0 + row;
        uint4 qv = z4;
        if (np < NP_) qv = *(const uint4*)(qb + (long)np*D_ + h*HD_ + c8);
        *(uint4*)(Qs + row*64 + c8) = qv;
        uint4 kv = z4;
        if (row < R_) kv = *(const uint4*)(kb + (long)row*D_ + h*HD_ + c8);
        *(uint4*)(Ks + row*64 + c8) = kv;
    }
    #pragma unroll
    for (int i = 0; i < 4; i++) {
        int id = t + i*256;
        int e = id >> 4, c8 = (id & 15) * 8;
        *(uint4*)(Vs + e*128 + c8) = *(const uint4*)(vT + ((long)h*HD_ + e)*128 + c8);
    }
    __syncthreads();
    int wv = t >> 6, lane = t & 63;
    int quad = lane >> 4, lm = lane & 15;
    int wm = (wv >> 1) * 64, wn = (wv & 1) * 64;
    int side = wv & 1;

    v4f acc[4][4];
    #pragma unroll
    for (int i = 0; i < 4; i++)
        #pragma unroll
        for (int j = 0; j < 4; j++)
            acc[i][j] = (v4f){0.f,0.f,0.f,0.f};
    #pragma unroll
    for (int k0 = 0; k0 < 64; k0 += 32) {
        v8s a[4], b[4];
        #pragma unroll
        for (int i = 0; i < 4; i++) a[i] = *(const v8s*)(Qs + (wm + i*16 + lm)*64 + k0 + quad*8);
        #pragma unroll
        for (int j = 0; j < 4; j++) b[j] = *(const v8s*)(Ks + (wn + j*16 + lm)*64 + k0 + quad*8);
        #pragma unroll
        for (int i = 0; i < 4; i++)
            #pragma unroll
            for (int j = 0; j < 4; j++)
                acc[i][j] = __builtin_amdgcn_mfma_f32_16x16x32_bf16(a[i], b[j], acc[i][j], 0, 0, 0);
    }
    // scale + mask cols >= 97
    #pragma unroll
    for (int j = 0; j < 4; j++) {
        int col = wn + j*16 + lm;
        bool ok = col < R_;
        #pragma unroll
        for (int i = 0; i < 4; i++)
            #pragma unroll
            for (int reg = 0; reg < 4; reg++)
                acc[i][j][reg] = ok ? acc[i][j][reg]*SCALE_ : -1e30f;
    }
    #pragma unroll
    for (int i = 0; i < 4; i++)
        #pragma unroll
        for (int reg = 0; reg < 4; reg++) {
            float m = fmaxf(fmaxf(acc[i][0][reg], acc[i][1][reg]),
                            fmaxf(acc[i][2][reg], acc[i][3][reg]));
            #pragma unroll
            for (int o = 1; o < 16; o <<= 1) m = fmaxf(m, __shfl_xor(m, o));
            if (lm == 0) rowm[side][wm + i*16 + quad*4 + reg] = m;
        }
    __syncthreads();
    #pragma unroll
    for (int i = 0; i < 4; i++)
        #pragma unroll
        for (int reg = 0; reg < 4; reg++) {
            int r = wm + i*16 + quad*4 + reg;
            float m = fmaxf(rowm[0][r], rowm[1][r]);
            float s = 0.f;
            #pragma unroll
            for (int j = 0; j < 4; j++) {
                float e = expf(acc[i][j][reg] - m);
                acc[i][j][reg] = e;
                s += e;
            }
            #pragma unroll
            for (int o = 1; o < 16; o <<= 1) s += __shfl_xor(s, o);
            if (lm == 0) rowl[side][r] = s;
        }
    __syncthreads();
    #pragma unroll
    for (int i = 0; i < 4; i++)
        #pragma unroll
        for (int reg = 0; reg < 4; reg++) {
            int r = wm + i*16 + quad*4 + reg;
            float inv = 1.0f / (rowl[0][r] + rowl[1][r]);
            #pragma unroll
            for (int j = 0; j < 4; j++)
                Ps[r*128 + wn + j*16 + lm] = f2bf(acc[i][j][reg] * inv);
        }
    __syncthreads();
    v4f acc2[2][4];
    #pragma unroll
    for (int i = 0; i < 2; i++)
        #pragma unroll
        for (int j = 0; j < 4; j++)
            acc2[i][j] = (v4f){0.f,0.f,0.f,0.f};
    int wm2 = wv * 32;
    #pragma unroll
    for (int k0 = 0; k0 < 128; k0 += 32) {
        v8s a2[2], b2[4];
        #pragma unroll
        for (int i = 0; i < 2; i++) a2[i] = *(const v8s*)(Ps + (wm2 + i*16 + lm)*128 + k0 + quad*8);
        #pragma unroll
        for (int j = 0; j < 4; j++) b2[j] = *(const v8s*)(Vs + (j*16 + lm)*128 + k0 + quad*8);
        #pragma unroll
        for (int i = 0; i < 2; i++)
            #pragma unroll
            for (int j = 0; j < 4; j++)
                acc2[i][j] = __builtin_amdgcn_mfma_f32_16x16x32_bf16(a2[i], b2[j], acc2[i][j], 0, 0, 0);
    }
    #pragma unroll
    for (int i = 0; i < 2; i++)
        #pragma unroll
        for (int j = 0; j < 4; j++)
            #pragma unroll
            for (int reg = 0; reg < 4; reg++) {
                int row = m0 + wm2 + i*16 + quad*4 + reg;
                if (row >= NP_) continue;
                int e = j*16 + lm;
                ushort bvv = f2bf(acc2[i][j][reg]);
                o1b[(long)row*D_ + h*HD_ + e] = bvv;
                int n = row / P_;
                int q = row - n*P_;
                o1T[(((long)(n*H_ + h))*HD_ + e)*576 + q] = bvv;
            }
}

// ---------------- fused attn2 (flash-style): scores2 + online softmax + P@V ----------------
__global__ __launch_bounds__(256) void k_attn2f(
        const ushort* __restrict__ o1b, const ushort* __restrict__ o1T, float* __restrict__ o2) {
    int qt = blockIdx.x;
    int zz = blockIdx.y;
    int n = zz / H_, h = zz % H_;
    int q0 = qt * 128;
    __shared__ ushort Qs[128*64];
    __shared__ ushort KV[128*64];
    __shared__ ushort Ps[128*128];
    __shared__ float rowm[2][128], rowl[2][128];
    __shared__ float mrun[128], lrun[128], alphaS[128];
    int t = threadIdx.x;
    const ushort* base = o1b + (long)n*P_*D_ + h*HD_;
    const uint4 z4 = {0u,0u,0u,0u};
    #pragma unroll
    for (int i = 0; i < 4; i++) {
        int id = t + i*256;
        int row = id >> 3, c8 = (id & 7) * 8;
        int q = q0 + row;
        uint4 v = z4;
        if (q < P_) v = *(const uint4*)(base + (long)q*D_ + c8);
        *(uint4*)(Qs + row*64 + c8) = v;
    }
    if (t < 128) { mrun[t] = -1e30f; lrun[t] = 0.f; }
    __syncthreads();
    int wv = t >> 6, lane = t & 63;
    int quad = lane >> 4, lm = lane & 15;
    int wm = (wv >> 1) * 64, wn = (wv & 1) * 64;
    int side = wv & 1;
    int wm2 = wv * 32;
    v4f acc2[2][4];
    #pragma unroll
    for (int i = 0; i < 2; i++)
        #pragma unroll
        for (int j = 0; j < 4; j++)
            acc2[i][j] = (v4f){0.f,0.f,0.f,0.f};

    for (int c = 0; c < 5; c++) {
        #pragma unroll
        for (int i = 0; i < 4; i++) {
            int id = t + i*256;
            int row = id >> 3, c8 = (id & 7) * 8;
            int q = c*128 + row;
            uint4 v = z4;
            if (q < P_) v = *(const uint4*)(base + (long)q*D_ + c8);
            *(uint4*)(KV + row*64 + c8) = v;
        }
        __syncthreads();
        v4f acc[4][4];
        #pragma unroll
        for (int i = 0; i < 4; i++)
            #pragma unroll
            for (int j = 0; j < 4; j++)
                acc[i][j] = (v4f){0.f,0.f,0.f,0.f};
        #pragma unroll
        for (int k0 = 0; k0 < 64; k0 += 32) {
            v8s a[4], b[4];
            #pragma unroll
            for (int i = 0; i < 4; i++) a[i] = *(const v8s*)(Qs + (wm + i*16 + lm)*64 + k0 + quad*8);
            #pragma unroll
            for (int j = 0; j < 4; j++) b[j] = *(const v8s*)(KV + (wn + j*16 + lm)*64 + k0 + quad*8);
            #pragma unroll
            for (int i = 0; i < 4; i++)
                #pragma unroll
                for (int j = 0; j < 4; j++)
                    acc[i][j] = __builtin_amdgcn_mfma_f32_16x16x32_bf16(a[i], b[j], acc[i][j], 0, 0, 0);
        }
        #pragma unroll
        for (int j = 0; j < 4; j++) {
            int col = c*128 + wn + j*16 + lm;
            bool ok = col < P_;
            #pragma unroll
            for (int i = 0; i < 4; i++)
                #pragma unroll
                for (int reg = 0; reg < 4; reg++)
                    acc[i][j][reg] = ok ? acc[i][j][reg]*SCALE_ : -1e30f;
        }
        #pragma unroll
        for (int i = 0; i < 4; i++)
            #pragma unroll
            for (int reg = 0; reg < 4; reg++) {
                float m = fmaxf(fmaxf(acc[i][0][reg], acc[i][1][reg]),
                                fmaxf(acc[i][2][reg], acc[i][3][reg]));
                #pragma unroll
                for (int o = 1; o < 16; o <<= 1) m = fmaxf(m, __shfl_xor(m, o));
                if (lm == 0) rowm[side][wm + i*16 + quad*4 + reg] = m;
            }
        __syncthreads();
        #pragma unroll
        for (int i = 0; i < 4; i++)
            #pragma unroll
            for (int reg = 0; reg < 4; reg++) {
                int r = wm + i*16 + quad*4 + reg;
                float mc = fmaxf(rowm[0][r], rowm[1][r]);
                float mn = fmaxf(mrun[r], mc);
                float s = 0.f;
                #pragma unroll
                for (int j = 0; j < 4; j++) {
                    float e = expf(acc[i][j][reg] - mn);
                    acc[i][j][reg] = e;
                    s += e;
                }
                #pragma unroll
                for (int o = 1; o < 16; o <<= 1) s += __shfl_xor(s, o);
                if (lm == 0) rowl[side][r] = s;
            }
        __syncthreads();
        if (side == 0 && lm == 0) {
            #pragma unroll
            for (int i = 0; i < 4; i++)
                #pragma unroll
                for (int reg = 0; reg < 4; reg++) {
                    int r = wm + i*16 + quad*4 + reg;
                    float mo = mrun[r];
                    float mc = fmaxf(rowm[0][r], rowm[1][r]);
                    float mn = fmaxf(mo, mc);
                    float al = expf(mo - mn);
                    lrun[r] = lrun[r]*al + rowl[0][r] + rowl[1][r];
                    mrun[r] = mn;
                    alphaS[r] = al;
                }
        }
        #pragma unroll
        for (int i = 0; i < 4; i++) {
            int id = t + i*256;
            int e = id >> 4, c8 = (id & 15) * 8;
            uint4 v = z4;
            if (c*128 + c8 < P_) v = *(const uint4*)(o1T + ((long)zz*HD_ + e)*576 + c*128 + c8);
            *(uint4*)(KV + e*128 + c8) = v;
        }
        #pragma unroll
        for (int i = 0; i < 4; i++)
            #pragma unroll
            for (int reg = 0; reg < 4; reg++) {
                int r = wm + i*16 + quad*4 + reg;
                #pragma unroll
                for (int j = 0; j < 4; j++)
                    Ps[r*128 + wn + j*16 + lm] = f2bf(acc[i][j][reg]);
            }
        __syncthreads();
        #pragma unroll
        for (int i = 0; i < 2; i++) {
            #pragma unroll
            for (int reg = 0; reg < 4; reg++) {
                float al = alphaS[wm2 + i*16 + quad*4 + reg];
                #pragma unroll
                for (int j = 0; j < 4; j++)
                    acc2[i][j][reg] *= al;
            }
        }
        #pragma unroll
        for (int k0 = 0; k0 < 128; k0 += 32) {
            v8s a2[2], b2[4];
            #pragma unroll
            for (int i = 0; i < 2; i++) a2[i] = *(const v8s*)(Ps + (wm2 + i*16 + lm)*128 + k0 + quad*8);
            #pragma unroll
            for (int j = 0; j < 4; j++) b2[j] = *(const v8s*)(KV + (j*16 + lm)*128 + k0 + quad*8);
            #pragma unroll
            for (int i = 0; i < 2; i++)
                #pragma unroll
                for (int j = 0; j < 4; j++)
                    acc2[i][j] = __builtin_amdgcn_mfma_f32_16x16x32_bf16(a2[i], b2[j], acc2[i][j], 0, 0, 0);
        }
        __syncthreads();
    }
    #pragma unroll
    for (int i = 0; i < 2; i++)
        #pragma unroll
        for (int j = 0; j < 4; j++)
            #pragma unroll
            for (int reg = 0; reg < 4; reg++) {
                int row = wm2 + i*16 + quad*4 + reg;
                int q = q0 + row;
                if (q >= P_) continue;
                float l = lrun[row];
                o2[((long)n*P_ + q)*D_ + h*HD_ + j*16 + lm] = acc2[i][j][reg] / l;
            }
}

// ---------------- x = LN(htr + tanh(o2)) -> bf16 ----------------
__global__ void k_ln(const float* __restrict__ htr, const float* __restrict__ o2,
                     const float* __restrict__ g, const float* __restrict__ b,
                     ushort* __restrict__ bx) {
    int np = blockIdx.x;
    int t = threadIdx.x;
    __shared__ float red[256];
    float v[D_/256];
    float s = 0.f;
    #pragma unroll
    for (int i = 0; i < D_/256; i++) {
        int d = t + i*256;
        float val = htr[(long)np*D_ + d] + tanhf(o2[(long)np*D_ + d]);
        v[i] = val; s += val;
    }
    red[t] = s; __syncthreads();
    for (int s1 = 128; s1; s1 >>= 1) { if (t < s1) red[t] += red[t+s1]; __syncthreads(); }
    float mu = red[0] * (1.0f/D_);
    __syncthreads();
    float s2 = 0.f;
    #pragma unroll
    for (int i = 0; i < D_/256; i++) { float dx = v[i]-mu; s2 += dx*dx; }
    red[t] = s2; __syncthreads();
    for (int s1 = 128; s1; s1 >>= 1) { if (t < s1) red[t] += red[t+s1]; __syncthreads(); }
    float inv = rsqrtf(red[0]*(1.0f/D_) + 1e-5f);
    #pragma unroll
    for (int i = 0; i < D_/256; i++) {
        int d = t + i*256;
        bx[(long)np*D_ + d] = f2bf((v[i]-mu)*inv*g[d] + b[d]);
    }
}

extern "C" void kernel_launch(void* const* d_in, const int* in_sizes, int n_in,
                              void* d_out, int out_size, void* d_ws, size_t ws_size,
                              hipStream_t stream) {
    const float* seq   = (const float*)d_in[0];
    const float* att   = (const float*)d_in[1];
    const int*   epos  = (const int*)d_in[2];
    const int*   hts   = (const int*)d_in[3];
    const float* rels  = (const float*)d_in[4];
    const float* We    = (const float*)d_in[5];
    const float* be    = (const float*)d_in[6];
    const float* Wq    = (const float*)d_in[7];
    const float* bq    = (const float*)d_in[8];
    const float* Wk    = (const float*)d_in[9];
    const float* bk    = (const float*)d_in[10];
    const float* Wv    = (const float*)d_in[11];
    const float* bv    = (const float*)d_in[12];
    const float* ln_g  = (const float*)d_in[13];
    const float* ln_b  = (const float*)d_in[14];
    const float* Wc    = (const float*)d_in[15];
    const float* bc    = (const float*)d_in[16];
    float* out = (float*)d_out;
    float* w = (float*)d_ws;

    const int NP = NP_;  // 2208

    // ---- f32 workspace ----
    float* entEmb  = w;                                 //    73,728
    float* entAtt  = entEmb  + (size_t)N_*E_*D_;        // 1,179,648
    float* htr     = entAtt  + (size_t)N_*E_*H_*C_;     // 1,695,744
    float* o2      = htr     + (size_t)NP*D_;           // 1,695,744
    // ---- bf16 workspace ----
    ushort* bhtAtt = (ushort*)(o2 + (size_t)NP*D_);     // 2,260,992
    ushort* bcat   = bhtAtt + (size_t)NP*C_;            // 5,087,232
    ushort* seqT   = bcat  + (size_t)NP*D3_;            // 3,145,728
    ushort* WeT    = seqT  + (size_t)N_*D_*C_;          // 1,769,472
    ushort* WqT    = WeT   + (size_t)D_*D3_;            //   589,824 (W3T base)
    ushort* WkT    = WqT   + (size_t)D_*D_;             //   589,824
    ushort* WvT    = WkT   + (size_t)D_*D_;             //   589,824
    ushort* WcT    = WvT   + (size_t)D_*D_;             //    74,496
    ushort* relsB  = WcT   + (size_t)D_*R_;             //    74,496
    ushort* bhtr   = relsB + (size_t)R_*D_;             // 1,695,744
    ushort* bqb    = bhtr  + (size_t)NP*D_;             // 1,695,744
    ushort* bkb    = bqb   + (size_t)NP*D_;             //    74,496
    ushort* vT     = bkb   + (size_t)R_*D_;             //    98,304 (768 x 128)
    ushort* o1b    = vT    + (size_t)D_*128;            // 1,695,744
    ushort* o1T    = o1b   + (size_t)NP*D_;             // 1,769,472 (48 x 64 x 576)
    ushort* bxb    = o1T   + (size_t)48*HD_*576;        // 1,695,744

    // 1: all transposes + casts
    k_prep<<<6697, 256, 0, stream>>>(seq, We, Wq, Wk, Wv, Wc, rels,
                                     seqT, WeT, WqT, WcT, relsB);
    // 2: ent_emb + ent_att
    k_ent<<<4896, 256, 0, stream>>>(seq, att, epos, entEmb, entAtt);
    // 3: gather + ht_att
    k_gath<<<8832, 256, 0, stream>>>(entEmb, entAtt, hts, bcat, bhtAtt);

    // 4: rs = batched bhtAtt(n) @ seqT(n)^T -> bcat[:, 2D:3D]
    k_mfma_bt<<<dim3(6, 5, N_), 256, 0, stream>>>(
        bhtAtt, seqT, nullptr, nullptr, bcat + 2*D_,
        P_, D_, D_, C_, C_, C_, 0, D3_, 1,
        (long)P_*C_, 0, (long)D_*C_, 0, 0, 0, (long)P_*D3_, 0, 0, 0);

    // 5: htr = tanh(bcat @ WeT^T + be) -> f32 htr + bf16 bhtr
    k_mfma_bt<<<dim3(6, 18, 1), 256, 0, stream>>>(
        bcat, WeT, be, htr, bhtr,
        NP, D_, D_, D3_, D3_, D3_, D_, D_, 1,
        0, 0, 0, 0, 0, 0, 0, 0, 1, 0);

    // 6: q = bhtr @ WqT^T + bq -> bf16 bqb
    k_mfma_bt<<<dim3(6, 18, 1), 256, 0, stream>>>(
        bhtr, WqT, bq, nullptr, bqb,
        NP, D_, D_, D_, D_, D_, 0, D_, 1,
        0, 0, 0, 0, 0, 0, 0, 0, 0, 0);

    // 7: k = relsB @ WkT^T + bk -> bf16 bkb (97 x 768)
    k_mfma_bt<<<dim3(6, 1, 1), 256, 0, stream>>>(
        relsB, WkT, bk, nullptr, bkb,
        R_, D_, D_, D_, D_, D_, 0, D_, 1,
        0, 0, 0, 0, 0, 0, 0, 0, 0, 0);

    // 8: vT = (rels @ Wv)^T + bv (per-row bias) -> bf16 vT (768 x 128, cols>=97 zero)
    k_mfma_bt<<<dim3(1, 6, 1), 256, 0, stream>>>(
        WvT, relsB, bv, nullptr, vT,
        D_, R_, 128, D_, D_, D_, 0, 128, 1,
        0, 0, 0, 0, 0, 0, 0, 0, 0, 1);

    // 9: fused attn1 -> o1b + o1T
    k_attn1f<<<dim3(18, 12), 256, 0, stream>>>(bqb, bkb, vT, o1b, o1T);

    // 10: fused attn2 (flash) -> o2 f32
    k_attn2f<<<dim3(5, 48), 256, 0, stream>>>(o1b, o1T, o2);

    // 11: x = LN(htr + tanh(o2)) -> bf16
    k_ln<<<NP, 256, 0, stream>>>(htr, o2, ln_g, ln_b, bxb);

    // 12: logits = bxb @ WcT^T + bc -> f32 out
    k_mfma_bt<<<dim3(1, 18, 1), 256, 0, stream>>>(
        bxb, WcT, bc, out, nullptr,
        NP, R_, R_, D_, D_, D_, R_, 0, 1,
        0, 0, 0, 0, 0, 0, 0, 0, 0, 0);
}